// Round 4
// baseline (610.666 us; speedup 1.0000x reference)
//
#include <hip/hip_runtime.h>
#include <hip/hip_bf16.h>
#include <cstdint>
#include <cstddef>

// ---------------------------------------------------------------------------
// EnhancedBVHRouter forward, MI355X/gfx950. Round 4.
// GEMM1: 256x256 tile, BK=32, 8 waves, 128KB dbuf LDS, counted-vmcnt pipeline
// (T3+T4+T5): B via pure global_load_lds from pre-swizzled image; A f32 loaded
// 2 tiles ahead into named reg sets, converted to bf16 hi/lo and ds_written.
// Raw s_barrier + asm lgkmcnt(0); the compiler's own wait on the A-reg use
// provides the counted vmcnt(8) (B issued before A => covered, in-order).
// Tail: round-3 kernels unchanged.
// ---------------------------------------------------------------------------

typedef short  s8v  __attribute__((ext_vector_type(8)));
typedef float  f4v  __attribute__((ext_vector_type(4)));
typedef float  f16v __attribute__((ext_vector_type(16)));
typedef unsigned int u32;

#define B_ROWS 32768

__device__ inline short f2bf(float x) {
    __hip_bfloat16 h = __float2bfloat16(x);
    return __builtin_bit_cast(short, h);
}
__device__ inline float bf2f(short s) {
    return __bfloat162float(__builtin_bit_cast(__hip_bfloat16, s));
}
__device__ inline float gelu_f(float x) {
    return 0.5f * x * (1.0f + erff(x * 0.70710678118654752440f));
}
__device__ inline void gload_lds16(const short* g, short* l) {
    __builtin_amdgcn_global_load_lds(
        (const __attribute__((address_space(1))) u32*)g,
        (__attribute__((address_space(3))) u32*)l, 16, 0, 0);
}

// ---------------------------------------------------------------------------
// W1 -> LDS-image: img[t][n][p]: t = K/32 step (64), n = col (512), p = phys
// 16B slot (8). Content slot cs = p ^ (n & 7); cs<4 -> hi chunk cs, cs>=4 ->
// lo chunk cs-4; chunk c covers k = t*32 + c*8 .. +8.
// ---------------------------------------------------------------------------
__global__ void split_w1_img(const float* __restrict__ W, short* __restrict__ img)
{
    const int idx = blockIdx.x * 256 + threadIdx.x;     // 64*512*8 total
    const int p = idx & 7;
    const int n = (idx >> 3) & 511;
    const int t = idx >> 12;
    const int cs = p ^ (n & 7);
    const int plane = cs >> 2, kc = cs & 3;
    const int kbase = t * 32 + kc * 8;
    s8v v8;
    #pragma unroll
    for (int e = 0; e < 8; ++e) {
        const float v = W[(size_t)(kbase + e) * 512 + n];
        const short h = f2bf(v);
        v8[e] = plane ? f2bf(v - bf2f(h)) : h;
    }
    *(s8v*)&img[(size_t)((t * 512 + n) * 64 + p * 8)] = v8;
}

// ---------------------------------------------------------------------------
// GEMM1: out[32768][512] = gelu(x @ W1 + b1), bf16x3, pipelined.
// ---------------------------------------------------------------------------
struct ARegs { f4v v[4]; };

__launch_bounds__(512, 1)
__global__ void gemmA(const float* __restrict__ X,
                      const short* __restrict__ Bimg,
                      const float* __restrict__ bias,
                      float* __restrict__ out)
{
    extern __shared__ short smem[];            // 2 * 32768 shorts = 128 KiB
    constexpr int NT = 64;                     // K/32
    short* const buf0 = smem;
    short* const buf1 = smem + 32768;          // per buf: A [256][64], B [256][64] @+16384

    const int tid = threadIdx.x;
    const int l = tid & 63, wid = tid >> 6;
    const int wr = wid >> 2, wc = wid & 3;     // 2 x 4 wave grid

    // bijective XCD swizzle: n-tile = bit2(d), m-tile = (d&3)*32 + d>>3.
    // XCDs 0-3 -> n0=0, XCDs 4-7 -> n0=256: 2MB B panel L2-resident per XCD.
    const int d = blockIdx.x;                  // 256 blocks
    const int n0 = ((d >> 2) & 1) * 256;
    const int m0 = ((d & 3) * 32 + (d >> 3)) * 256;

    // A staging: thread -> (row tid>>1, 16-float k-half tid&1)
    const int arow = tid >> 1, ahalf = tid & 1;
    const float* xP = X + (size_t)(m0 + arow) * 2048 + ahalf * 16;
    const int aoff = arow * 64;
    const int ps0 = ((ahalf * 2    ) ^ (arow & 7)) * 8;   // hi chunk 2h
    const int ps1 = ((ahalf * 2 + 1) ^ (arow & 7)) * 8;   // hi chunk 2h+1
    const int ps2 = ((ahalf * 2 + 4) ^ (arow & 7)) * 8;   // lo
    const int ps3 = ((ahalf * 2 + 5) ^ (arow & 7)) * 8;

    // B staging: 4 DMA/wave, fully linear (image pre-swizzled)
    const short* bgl = Bimg + (size_t)(n0 + wid * 32) * 64 + l * 8;
    const int bdo = 16384 + wid * 2048;        // LDS short-offset of wave's B dest

    f16v acc[4][2];
    #pragma unroll
    for (int m = 0; m < 4; ++m) { acc[m][0] = (f16v)0.0f; acc[m][1] = (f16v)0.0f; }

    auto stageB = [&](int t, short* buf) {
        const short* bt = bgl + (size_t)t * 32768;
        short* bd = buf + bdo;
        gload_lds16(bt,        bd);
        gload_lds16(bt +  512, bd + 512);
        gload_lds16(bt + 1024, bd + 1024);
        gload_lds16(bt + 1536, bd + 1536);
    };
    auto loadA = [&](int t, ARegs& r) {
        const float* p = xP + t * 32;
        r.v[0] = *(const f4v*)(p);
        r.v[1] = *(const f4v*)(p + 4);
        r.v[2] = *(const f4v*)(p + 8);
        r.v[3] = *(const f4v*)(p + 12);
    };
    auto cvtWrite = [&](const ARegs& r, short* buf) {
        s8v hi0, hi1, lo0, lo1;
        #pragma unroll
        for (int e = 0; e < 4; ++e) {
            float v; short h;
            v = r.v[0][e]; h = f2bf(v); hi0[e]     = h; lo0[e]     = f2bf(v - bf2f(h));
            v = r.v[1][e]; h = f2bf(v); hi0[e + 4] = h; lo0[e + 4] = f2bf(v - bf2f(h));
            v = r.v[2][e]; h = f2bf(v); hi1[e]     = h; lo1[e]     = f2bf(v - bf2f(h));
            v = r.v[3][e]; h = f2bf(v); hi1[e + 4] = h; lo1[e + 4] = f2bf(v - bf2f(h));
        }
        short* aw = buf + aoff;
        *(s8v*)&aw[ps0] = hi0;
        *(s8v*)&aw[ps1] = hi1;
        *(s8v*)&aw[ps2] = lo0;
        *(s8v*)&aw[ps3] = lo1;
    };
    auto compute = [&](const short* buf) {
        const short* Ab = buf;
        const short* Bb = buf + 16384;
        #pragma unroll
        for (int ks = 0; ks < 2; ++ks) {
            const int c0 = ks * 2 + (l >> 5);
            s8v ahf[4], alf[4], bhf[2], blf[2];
            #pragma unroll
            for (int m = 0; m < 4; ++m) {
                const int row = wr * 128 + m * 32 + (l & 31);
                const int ph = c0 ^ (row & 7);
                ahf[m] = *(const s8v*)&Ab[row * 64 + ph * 8];
                alf[m] = *(const s8v*)&Ab[row * 64 + (ph ^ 4) * 8];
            }
            #pragma unroll
            for (int n = 0; n < 2; ++n) {
                const int col = wc * 64 + n * 32 + (l & 31);
                const int ph = c0 ^ (col & 7);
                bhf[n] = *(const s8v*)&Bb[col * 64 + ph * 8];
                blf[n] = *(const s8v*)&Bb[col * 64 + (ph ^ 4) * 8];
            }
            __builtin_amdgcn_s_setprio(1);
            #pragma unroll
            for (int m = 0; m < 4; ++m)
                #pragma unroll
                for (int n = 0; n < 2; ++n) {
                    acc[m][n] = __builtin_amdgcn_mfma_f32_32x32x16_bf16(ahf[m], bhf[n], acc[m][n], 0, 0, 0);
                    acc[m][n] = __builtin_amdgcn_mfma_f32_32x32x16_bf16(ahf[m], blf[n], acc[m][n], 0, 0, 0);
                    acc[m][n] = __builtin_amdgcn_mfma_f32_32x32x16_bf16(alf[m], bhf[n], acc[m][n], 0, 0, 0);
                }
            __builtin_amdgcn_s_setprio(0);
        }
    };

    ARegs arA, arB;

    // prologue: B(0) first (older), then A(0), A(1); cvt A(0) waits vmcnt(4)
    stageB(0, buf0);
    loadA(0, arA);
    loadA(1, arB);
    __builtin_amdgcn_sched_barrier(0);
    cvtWrite(arA, buf0);
    asm volatile("s_waitcnt lgkmcnt(0)" ::: "memory");
    __builtin_amdgcn_s_barrier();

    // body(t): stage B(t+1) -> bufN; load A(t+2) -> ld; cvt cv(=A(t+1)) -> bufN;
    // waits; barrier; compute bufC; barrier.
    auto body = [&](int t, short* bufC, short* bufN, ARegs& ld, ARegs& cv) {
        const bool doStage = (t + 1 < NT);
        if (doStage) stageB(t + 1, bufN);          // B older than A within iter
        if (t + 2 < NT) loadA(t + 2, ld);
        __builtin_amdgcn_sched_barrier(0);
        if (doStage) cvtWrite(cv, bufN);           // implicit wait: vmcnt(<=8), covers B(t)
        if (t == NT - 1)
            asm volatile("s_waitcnt vmcnt(0)" ::: "memory");   // B(NT-1) not covered by a cvt
        asm volatile("s_waitcnt lgkmcnt(0)" ::: "memory");
        __builtin_amdgcn_s_barrier();
        compute(bufC);
        __builtin_amdgcn_s_barrier();
    };

    for (int tp = 0; tp < NT; tp += 2) {
        body(tp,     buf0, buf1, arA, arB);   // cvt arB = A(tp+1); load A(tp+2)->arA
        body(tp + 1, buf1, buf0, arB, arA);   // cvt arA = A(tp+2); load A(tp+3)->arB
    }

    // epilogue: gelu(acc + bias) -> out (f32)
    #pragma unroll
    for (int m = 0; m < 4; ++m) {
        #pragma unroll
        for (int n = 0; n < 2; ++n) {
            const int gcol = n0 + wc * 64 + n * 32 + (l & 31);
            const float bv = bias[gcol];
            #pragma unroll
            for (int r = 0; r < 16; ++r) {
                const int grow = m0 + wr * 128 + m * 32
                               + (r & 3) + 8 * (r >> 2) + 4 * (l >> 5);
                out[(size_t)grow * 512 + gcol] = gelu_f(acc[m][n][r] + bv);
            }
        }
    }
}

// ---------------------------------------------------------------------------
// Fused weight split (tail weights): W (K x N f32) -> [2][N][Kpad] bf16 planes.
// ---------------------------------------------------------------------------
struct SplitDesc { const float* W; short* dst; int K, N, Kpad, blk0; };
struct SplitPack { SplitDesc d[9]; };

__global__ void split_all(SplitPack p) {
    const int bid = blockIdx.x;
    int i = 0;
    #pragma unroll
    for (int j = 1; j < 9; ++j) if (bid >= p.d[j].blk0) i = j;
    const SplitDesc& D = p.d[i];
    const int idx = (bid - D.blk0) * 256 + threadIdx.x;
    const int total = D.N * D.Kpad;
    if (idx >= total) return;
    const int n = idx / D.Kpad, k = idx - n * D.Kpad;
    const float v = (k < D.K) ? D.W[(size_t)k * D.N + n] : 0.0f;
    const short hs = f2bf(v);
    D.dst[idx] = hs;
    D.dst[total + idx] = f2bf(v - bf2f(hs));
}

// ---------------------------------------------------------------------------
// Tail GEMM: bf16x3, 32x32x16, BK=32, dbuf LDS, 2-phase prefetch.
// ---------------------------------------------------------------------------
template<int BM, int BN, int EPI>
__launch_bounds__(256, 2)
__global__ void gemm32(const float* __restrict__ A, int lda,
                       const short* __restrict__ Bsp, int ldb, int NK,
                       const float* __restrict__ bias, int K, int N, int ntiles,
                       float* __restrict__ out, float* __restrict__ out2)
{
    constexpr int MF  = BM / 64;
    constexpr int NFw = BN / 64;
    constexpr int BUF = (BM + BN) * 64;
    constexpr int FPT = BM / 8;
    constexpr int TPR = 32 / FPT;
    constexpr int nBI = BN / 32;
    __shared__ short smem[2 * BUF];

    const int tid = threadIdx.x;
    const int l   = tid & 63, wid = tid >> 6;
    const int wr  = wid >> 1, wc = wid & 1;
    const int bid = blockIdx.x;
    const int ntb = bid % ntiles, mtb = bid / ntiles;
    const int m0  = mtb * BM, n0 = ntb * BN;

    const int ar = tid / TPR, aseg = tid % TPR;
    const float* aP = A + (size_t)(m0 + ar) * lda + aseg * FPT;

    const short* bg[nBI];
    {
        const int cs = (l & 7) ^ (l >> 3);
        const int plane = cs >> 2, kslot = cs & 3;
        #pragma unroll
        for (int j = 0; j < nBI; ++j) {
            const int col = (wid * nBI + j) * 8 + (l >> 3);
            bg[j] = Bsp + (size_t)plane * NK + (size_t)(n0 + col) * ldb + kslot * 8;
        }
    }

    f16v acc[MF][NFw];
    #pragma unroll
    for (int m = 0; m < MF; ++m)
        #pragma unroll
        for (int n = 0; n < NFw; ++n) acc[m][n] = (f16v)0.0f;

    f4v areg[FPT / 4];

    auto loadA = [&](int t) {
        const float* p = aP + t * 32;
        #pragma unroll
        for (int i = 0; i < FPT / 4; ++i) areg[i] = *(const f4v*)(p + i * 4);
    };
    auto stageB = [&](int t, short* buf) {
        short* Bb = buf + BM * 64;
        #pragma unroll
        for (int j = 0; j < nBI; ++j)
            gload_lds16(bg[j] + t * 32, Bb + (wid * nBI + j) * 512);
    };
    auto writeA = [&](short* buf) {
        #pragma unroll
        for (int c = 0; c < FPT / 8; ++c) {
            s8v hi, lo;
            #pragma unroll
            for (int e = 0; e < 8; ++e) {
                const float v = areg[c * 2 + (e >> 2)][e & 3];
                const short hs = f2bf(v);
                hi[e] = hs; lo[e] = f2bf(v - bf2f(hs));
            }
            const int csh = aseg * (FPT / 8) + c;
            *(s8v*)&buf[ar * 64 + ((csh    ) ^ (ar & 7)) * 8] = hi;
            *(s8v*)&buf[ar * 64 + ((csh + 4) ^ (ar & 7)) * 8] = lo;
        }
    };
    auto compute = [&](const short* buf) {
        const short* Ab = buf;
        const short* Bb = buf + BM * 64;
        #pragma unroll
        for (int ks = 0; ks < 2; ++ks) {
            const int csb = ks * 2 + (l >> 5);
            s8v ah[MF], al[MF], bh[NFw], bl[NFw];
            #pragma unroll
            for (int m = 0; m < MF; ++m) {
                const int row = wr * (BM / 2) + m * 32 + (l & 31);
                ah[m] = *(const s8v*)&Ab[row * 64 + ((csb    ) ^ (row & 7)) * 8];
                al[m] = *(const s8v*)&Ab[row * 64 + ((csb + 4) ^ (row & 7)) * 8];
            }
            #pragma unroll
            for (int n = 0; n < NFw; ++n) {
                const int col = wc * (BN / 2) + n * 32 + (l & 31);
                bh[n] = *(const s8v*)&Bb[col * 64 + ((csb    ) ^ (col & 7)) * 8];
                bl[n] = *(const s8v*)&Bb[col * 64 + ((csb + 4) ^ (col & 7)) * 8];
            }
            __builtin_amdgcn_s_setprio(1);
            #pragma unroll
            for (int m = 0; m < MF; ++m)
                #pragma unroll
                for (int n = 0; n < NFw; ++n) {
                    acc[m][n] = __builtin_amdgcn_mfma_f32_32x32x16_bf16(ah[m], bh[n], acc[m][n], 0, 0, 0);
                    acc[m][n] = __builtin_amdgcn_mfma_f32_32x32x16_bf16(ah[m], bl[n], acc[m][n], 0, 0, 0);
                    acc[m][n] = __builtin_amdgcn_mfma_f32_32x32x16_bf16(al[m], bh[n], acc[m][n], 0, 0, 0);
                }
            __builtin_amdgcn_s_setprio(0);
        }
    };

    const int NT = K / 32;
    loadA(0);
    stageB(0, smem);
    writeA(smem);
    __syncthreads();
    for (int t = 0; t < NT; ++t) {
        short* curb = smem + (t & 1) * BUF;
        short* nxtb = smem + ((t & 1) ^ 1) * BUF;
        const bool pf = (t + 1 < NT);
        if (pf) { loadA(t + 1); stageB(t + 1, nxtb); }
        compute(curb);
        if (pf) writeA(nxtb);
        __syncthreads();
    }

    if constexpr (EPI <= 1) {
        #pragma unroll
        for (int m = 0; m < MF; ++m) {
            #pragma unroll
            for (int n = 0; n < NFw; ++n) {
                const int gcol = n0 + wc * (BN / 2) + n * 32 + (l & 31);
                const float bv = bias[gcol];
                #pragma unroll
                for (int r = 0; r < 16; ++r) {
                    const int grow = m0 + wr * (BM / 2) + m * 32
                                   + (r & 3) + 8 * (r >> 2) + 4 * (l >> 5);
                    float xv = acc[m][n][r] + bv;
                    if constexpr (EPI == 0) xv = gelu_f(xv);
                    out[(size_t)grow * N + gcol] = xv;
                }
            }
        }
    } else {
        float* LT = reinterpret_cast<float*>(smem);
        const int gcolL = wc * 32 + (l & 31);
        const float bv = bias[gcolL];
        #pragma unroll
        for (int r = 0; r < 16; ++r) {
            const int row = wr * 32 + (r & 3) + 8 * (r >> 2) + 4 * (l >> 5);
            LT[row * 64 + gcolL] = acc[0][0][r] + bv;
        }
        __syncthreads();
        const int r = tid >> 2, q = tid & 3;
        const float* Lr = LT + r * 64 + q * 16;
        float mx = Lr[0];
        #pragma unroll
        for (int c = 1; c < 16; ++c) mx = fmaxf(mx, Lr[c]);
        mx = fmaxf(mx, __shfl_xor(mx, 1));
        mx = fmaxf(mx, __shfl_xor(mx, 2));
        float ev[16]; float s = 0.0f;
        #pragma unroll
        for (int c = 0; c < 16; ++c) { ev[c] = expf(Lr[c] - mx); s += ev[c]; }
        s += __shfl_xor(s, 1);
        s += __shfl_xor(s, 2);
        float pmax = -1.0f; int arg = 0;
        #pragma unroll
        for (int c = 0; c < 16; ++c) {
            const float pv = ev[c] / s;
            out[(size_t)(m0 + r) * 64 + q * 16 + c] = pv;
            if (pv > pmax) { pmax = pv; arg = q * 16 + c; }
        }
        #pragma unroll
        for (int off = 1; off <= 2; off <<= 1) {
            const float po = __shfl_xor(pmax, off);
            const int   ao = __shfl_xor(arg, off);
            if (po > pmax || (po == pmax && ao < arg)) { pmax = po; arg = ao; }
        }
        if (q == 0) out2[m0 + r] = (float)arg;
    }
}

// ---------------------------------------------------------------------------
__global__ __launch_bounds__(256) void ln_kernel(float* __restrict__ H,
                                                 const float* __restrict__ G,
                                                 const float* __restrict__ Bv)
{
    const int row = blockIdx.x * 4 + (threadIdx.x >> 6);
    const int l   = threadIdx.x & 63;
    float* hr = H + (size_t)row * 256;
    f4v v = *reinterpret_cast<const f4v*>(&hr[l * 4]);
    float s = v[0] + v[1] + v[2] + v[3];
    #pragma unroll
    for (int o = 32; o; o >>= 1) s += __shfl_xor(s, o);
    const float mu = s * 0.00390625f;
    f4v d = v - mu;
    float q = d[0]*d[0] + d[1]*d[1] + d[2]*d[2] + d[3]*d[3];
    #pragma unroll
    for (int o = 32; o; o >>= 1) q += __shfl_xor(q, o);
    const float var = q * 0.00390625f;
    const float sc  = 1.0f / sqrtf(var + 1e-5f);
    f4v gg = *reinterpret_cast<const f4v*>(&G[l * 4]);
    f4v bb = *reinterpret_cast<const f4v*>(&Bv[l * 4]);
    f4v o4 = d * sc * gg + bb;
    *reinterpret_cast<f4v*>(&hr[l * 4]) = o4;
}

// ---------------------------------------------------------------------------
__global__ __launch_bounds__(256) void p_kernel(
    const float* __restrict__ X, int din,
    const float* __restrict__ F,
    const float* __restrict__ W3d, const float* __restrict__ b3d,
    const float* __restrict__ cc,
    const float* __restrict__ rW, const float* __restrict__ rb,
    float* __restrict__ P)
{
    const int row = blockIdx.x * 4 + (threadIdx.x >> 6);
    const int l   = threadIdx.x & 63;
    float px0 = 0.f, px1 = 0.f, px2 = 0.f;
    const int per = din >> 6;
    const float* xr = X + (size_t)row * din;
    for (int i = 0; i < per; ++i) {
        const int k = l + (i << 6);
        const float xv = xr[k];
        px0 += xv * W3d[k*3 + 0];
        px1 += xv * W3d[k*3 + 1];
        px2 += xv * W3d[k*3 + 2];
    }
    float g0 = 0.f, g1 = 0.f, g2 = 0.f, g3 = 0.f;
    const float* fr = F + (size_t)row * 128;
    #pragma unroll
    for (int i = 0; i < 2; ++i) {
        const int k = l + (i << 6);
        const float fv = fr[k];
        g0 += fv * rW[k*4 + 0]; g1 += fv * rW[k*4 + 1];
        g2 += fv * rW[k*4 + 2]; g3 += fv * rW[k*4 + 3];
    }
    #pragma unroll
    for (int o = 32; o; o >>= 1) {
        px0 += __shfl_xor(px0, o); px1 += __shfl_xor(px1, o); px2 += __shfl_xor(px2, o);
        g0  += __shfl_xor(g0, o);  g1  += __shfl_xor(g1, o);
        g2  += __shfl_xor(g2, o);  g3  += __shfl_xor(g3, o);
    }
    if (l == 0) {
        const float pos0 = px0 + b3d[0], pos1 = px1 + b3d[1], pos2 = px2 + b3d[2];
        float lg[4];
        float mx = -1e30f;
        float gg[4] = {g0, g1, g2, g3};
        #pragma unroll
        for (int c = 0; c < 4; ++c) {
            float a = gg[c] + rb[c]
                    + pos0 * rW[512 + c] + pos1 * rW[516 + c] + pos2 * rW[520 + c];
            const float d0 = pos0 - cc[c*3 + 0];
            const float d1 = pos1 - cc[c*3 + 1];
            const float d2 = pos2 - cc[c*3 + 2];
            a += 0.5f * (-(d0*d0 + d1*d1 + d2*d2) / 2.00000001f);
            lg[c] = a;
            mx = fmaxf(mx, a);
        }
        const float e0 = expf(lg[0]-mx), e1 = expf(lg[1]-mx),
                    e2 = expf(lg[2]-mx), e3 = expf(lg[3]-mx);
        const float s = e0 + e1 + e2 + e3;
        float* pr = P + (size_t)row * 4;
        pr[0] = e0/s; pr[1] = e1/s; pr[2] = e2/s; pr[3] = e3/s;
    }
}

// ---------------------------------------------------------------------------
__global__ void concat_kernel(const float* __restrict__ f3,
                              const float* __restrict__ P1,
                              const float* __restrict__ P2,
                              const float* __restrict__ P3,
                              float* __restrict__ C)
{
    const int idx = blockIdx.x * 256 + threadIdx.x;
    const int row = idx / 160, j = idx - row * 160;
    float v;
    if      (j < 128) v = f3[(size_t)row * 128 + j];
    else if (j < 132) v = P1[(size_t)row * 4 + (j - 128)];
    else if (j < 136) v = P2[(size_t)row * 4 + (j - 132)];
    else if (j < 140) v = P3[(size_t)row * 4 + (j - 136)];
    else              v = 0.0f;
    C[idx] = v;
}

// ---------------------------------------------------------------------------
extern "C" void kernel_launch(void* const* d_in, const int* in_sizes, int n_in,
                              void* d_out, int out_size, void* d_ws, size_t ws_size,
                              hipStream_t stream)
{
    (void)in_sizes; (void)n_in; (void)out_size; (void)ws_size;

    const float* x    = (const float*)d_in[0];
    const float* ipW1 = (const float*)d_in[1];
    const float* ipb1 = (const float*)d_in[2];
    const float* ipW2 = (const float*)d_in[3];
    const float* ipb2 = (const float*)d_in[4];
    const float* ln_g = (const float*)d_in[5];
    const float* ln_b = (const float*)d_in[6];
    const float* W3d[3] = {(const float*)d_in[7],  (const float*)d_in[17], (const float*)d_in[27]};
    const float* b3d[3] = {(const float*)d_in[8],  (const float*)d_in[18], (const float*)d_in[28]};
    const float* cc[3]  = {(const float*)d_in[9],  (const float*)d_in[19], (const float*)d_in[29]};
    const float* f1W[3] = {(const float*)d_in[11], (const float*)d_in[21], (const float*)d_in[31]};
    const float* f1b[3] = {(const float*)d_in[12], (const float*)d_in[22], (const float*)d_in[32]};
    const float* f2W[3] = {(const float*)d_in[13], (const float*)d_in[23], (const float*)d_in[33]};
    const float* f2b[3] = {(const float*)d_in[14], (const float*)d_in[24], (const float*)d_in[34]};
    const float* rW[3]  = {(const float*)d_in[15], (const float*)d_in[25], (const float*)d_in[35]};
    const float* rb[3]  = {(const float*)d_in[16], (const float*)d_in[26], (const float*)d_in[36]};
    const float* ehW1 = (const float*)d_in[37];
    const float* ehb1 = (const float*)d_in[38];
    const float* ehW2 = (const float*)d_in[39];
    const float* ehb2 = (const float*)d_in[40];

    size_t off = 0;
    auto take = [&](size_t bytes) -> void* {
        void* p = (char*)d_ws + off;
        off += (bytes + 255) & ~(size_t)255;
        return p;
    };
    auto takeW = [&](int N, int Kpad) -> short* {
        return (short*)take((size_t)2 * N * Kpad * 2);
    };
    short* W1img = (short*)take((size_t)64 * 512 * 64 * 2);   // 4 MiB LDS-image
    short* W2s = takeW(256, 512);
    short* L1a = takeW(128, 256);
    short* L1b = takeW(128, 128);
    short* L2a = takeW(128, 128);
    short* L2b = takeW(128, 128);
    short* L3a = takeW(128, 128);
    short* L3b = takeW(128, 128);
    short* E1s = takeW(256, 160);
    short* E2s = takeW(64, 256);
    float* h1 = (float*)take((size_t)B_ROWS * 512 * 4);
    float* h2 = (float*)take((size_t)B_ROWS * 256 * 4);
    float* zg = (float*)take((size_t)B_ROWS * 128 * 4);
    float* f1 = (float*)take((size_t)B_ROWS * 128 * 4);
    float* f2 = (float*)take((size_t)B_ROWS * 128 * 4);
    float* f3 = (float*)take((size_t)B_ROWS * 128 * 4);
    float* p1 = (float*)take((size_t)B_ROWS * 4 * 4);
    float* p2 = (float*)take((size_t)B_ROWS * 4 * 4);
    float* p3 = (float*)take((size_t)B_ROWS * 4 * 4);
    float* comb = h1;                                        // h1 dead by then
    float* geh  = (float*)((char*)h1 + ((size_t)22 << 20));

    // ---- weight pre-passes ----
    split_w1_img<<<(64 * 512 * 8) / 256, 256, 0, stream>>>(ipW1, W1img);
    SplitPack sp;
    int blk = 0;
    auto desc = [&](int i, const float* W, short* dst, int K, int N, int Kpad) {
        sp.d[i] = {W, dst, K, N, Kpad, blk};
        blk += (N * Kpad + 255) / 256;
    };
    desc(0, ipW2,   W2s,  512, 256,  512);
    desc(1, f1W[0], L1a,  256, 128,  256);
    desc(2, f2W[0], L1b,  128, 128,  128);
    desc(3, f1W[1], L2a,  128, 128,  128);
    desc(4, f2W[1], L2b,  128, 128,  128);
    desc(5, f1W[2], L3a,  128, 128,  128);
    desc(6, f2W[2], L3b,  128, 128,  128);
    desc(7, ehW1,   E1s,  140, 256,  160);
    desc(8, ehW2,   E2s,  256,  64,  256);
    split_all<<<blk, 256, 0, stream>>>(sp);

    const dim3 blkT(256);
    constexpr int MG128 = B_ROWS / 128;  // 256
    constexpr int MG64  = B_ROWS / 64;   // 512

    // input_proj
    gemmA<<<256, 512, 131072, stream>>>(x, W1img, ipb1, h1);
    gemm32<128,128,1><<<MG128*2, blkT, 0, stream>>>(h1,  512, W2s,  512, 256*512,  ipb2,  512, 256, 2, h2, nullptr);
    ln_kernel<<<B_ROWS/4, 256, 0, stream>>>(h2, ln_g, ln_b);

    // level 1 (din=256)
    gemm32<64,128,0><<<MG64, blkT, 0, stream>>>(h2, 256, L1a, 256, 128*256, f1b[0], 256, 128, 1, zg, nullptr);
    gemm32<64,128,1><<<MG64, blkT, 0, stream>>>(zg, 128, L1b, 128, 128*128, f2b[0], 128, 128, 1, f1, nullptr);
    p_kernel<<<B_ROWS/4, 256, 0, stream>>>(h2, 256, f1, W3d[0], b3d[0], cc[0], rW[0], rb[0], p1);

    // level 2 (din=128)
    gemm32<64,128,0><<<MG64, blkT, 0, stream>>>(f1, 128, L2a, 128, 128*128, f1b[1], 128, 128, 1, zg, nullptr);
    gemm32<64,128,1><<<MG64, blkT, 0, stream>>>(zg, 128, L2b, 128, 128*128, f2b[1], 128, 128, 1, f2, nullptr);
    p_kernel<<<B_ROWS/4, 256, 0, stream>>>(f1, 128, f2, W3d[1], b3d[1], cc[1], rW[1], rb[1], p2);

    // level 3 (din=128)
    gemm32<64,128,0><<<MG64, blkT, 0, stream>>>(f2, 128, L3a, 128, 128*128, f1b[2], 128, 128, 1, zg, nullptr);
    gemm32<64,128,1><<<MG64, blkT, 0, stream>>>(zg, 128, L3b, 128, 128*128, f2b[2], 128, 128, 1, f3, nullptr);
    p_kernel<<<B_ROWS/4, 256, 0, stream>>>(f2, 128, f3, W3d[2], b3d[2], cc[2], rW[2], rb[2], p3);

    // expert head
    concat_kernel<<<(B_ROWS*160)/256, 256, 0, stream>>>(f3, p1, p2, p3, comb);
    gemm32<64,128,0><<<MG64*2, blkT, 0, stream>>>(comb, 160, E1s, 160, 256*160, ehb1, 160, 256, 2, geh, nullptr);
    gemm32<64,64,2><<<MG64, blkT, 0, stream>>>(geh, 256, E2s, 256, 64*256, ehb2, 256, 64, 1,
                                               (float*)d_out, (float*)d_out + (size_t)B_ROWS * 64);
}

// Round 5
// 555.457 us; speedup vs baseline: 1.0994x; 1.0994x over previous
//
#include <hip/hip_runtime.h>
#include <hip/hip_bf16.h>
#include <cstdint>
#include <cstddef>

// ---------------------------------------------------------------------------
// EnhancedBVHRouter forward, MI355X/gfx950. Round 5.
// GEMM1: round-3 gemm1k (proven 288us, MfmaUtil 31.5%).
// Tail fused: levelk (gelu(x@Wa)@Wb in one kernel, g-tile via LDS),
// gemm2 with fused LayerNorm epilogue (BN=256), concat eliminated
// (strided writes into comb), p_kernel writes probs into comb directly.
// All GEMMs bf16x3 (hi/lo split, 3 MFMA), f32-class precision.
// ---------------------------------------------------------------------------

typedef short  s8v  __attribute__((ext_vector_type(8)));
typedef float  f4v  __attribute__((ext_vector_type(4)));
typedef float  f16v __attribute__((ext_vector_type(16)));
typedef unsigned int u32;

#define B_ROWS 32768

__device__ inline short f2bf(float x) {
    __hip_bfloat16 h = __float2bfloat16(x);
    return __builtin_bit_cast(short, h);
}
__device__ inline float bf2f(short s) {
    return __bfloat162float(__builtin_bit_cast(__hip_bfloat16, s));
}
__device__ inline float gelu_f(float x) {
    return 0.5f * x * (1.0f + erff(x * 0.70710678118654752440f));
}
__device__ inline void gload_lds16(const short* g, short* l) {
    __builtin_amdgcn_global_load_lds(
        (const __attribute__((address_space(1))) u32*)g,
        (__attribute__((address_space(3))) u32*)l, 16, 0, 0);
}

// ---------------------------------------------------------------------------
// W1 -> LDS-image: img[t][n][p]: t = K/32 step (64), n = col (512), p = phys
// 16B slot (8). Content slot cs = p ^ (n & 7); cs<4 -> hi chunk cs, cs>=4 ->
// lo chunk cs-4; chunk c covers k = t*32 + c*8 .. +8.
// ---------------------------------------------------------------------------
__global__ void split_w1_img(const float* __restrict__ W, short* __restrict__ img)
{
    const int idx = blockIdx.x * 256 + threadIdx.x;     // 64*512*8 total
    const int p = idx & 7;
    const int n = (idx >> 3) & 511;
    const int t = idx >> 12;
    const int cs = p ^ (n & 7);
    const int plane = cs >> 2, kc = cs & 3;
    const int kbase = t * 32 + kc * 8;
    s8v v8;
    #pragma unroll
    for (int e = 0; e < 8; ++e) {
        const float v = W[(size_t)(kbase + e) * 512 + n];
        const short h = f2bf(v);
        v8[e] = plane ? f2bf(v - bf2f(h)) : h;
    }
    *(s8v*)&img[(size_t)((t * 512 + n) * 64 + p * 8)] = v8;
}

// ---------------------------------------------------------------------------
// GEMM1: out[32768][512] = gelu(x @ W1 + b1), bf16x3. (round-3 proven kernel)
// BM=128, BN=128 (ntiles=4), BK=32, 256 thr / 4 waves 2x2, wave-tile 64x64.
// ---------------------------------------------------------------------------
__launch_bounds__(256, 4)
__global__ void gemm1k(const float* __restrict__ X,
                       const short* __restrict__ Bimg,
                       const float* __restrict__ bias,
                       float* __restrict__ out)
{
    __shared__ short smem[128 * 64 * 2];
    short* Ab = smem;
    short* Bb = smem + 128 * 64;

    const int tid = threadIdx.x;
    const int l = tid & 63, wid = tid >> 6;
    const int wr = wid >> 1, wc = wid & 1;

    const int d = blockIdx.x;                 // 1024 blocks
    const int xcd = d & 7;
    const int m0 = ((xcd & 1) * 128 + (d >> 3)) * 128;
    const int n0 = (xcd >> 1) * 128;

    const int ar = tid & 127, ah = tid >> 7;
    const float* xP = X + (size_t)(m0 + ar) * 2048 + ah * 16;
    short* awr = Ab + ar * 64;
    const int pw0 = ((ah * 2    ) ^ (ar & 7)) * 8;
    const int pw1 = ((ah * 2 + 1) ^ (ar & 7)) * 8;
    const int pw2 = ((ah * 2 + 4) ^ (ar & 7)) * 8;
    const int pw3 = ((ah * 2 + 5) ^ (ar & 7)) * 8;

    const short* bP = Bimg + (size_t)n0 * 64 + (size_t)(wid * 4) * 512 + (size_t)l * 8;
    short* bD = Bb + wid * 4 * 512;

    f16v acc[2][2];
    #pragma unroll
    for (int m = 0; m < 2; ++m)
        #pragma unroll
        for (int n = 0; n < 2; ++n) acc[m][n] = (f16v)0.0f;

    f4v cur0, cur1, cur2, cur3;
    cur0 = *(const f4v*)(xP + 0);
    cur1 = *(const f4v*)(xP + 4);
    cur2 = *(const f4v*)(xP + 8);
    cur3 = *(const f4v*)(xP + 12);

    for (int t = 0; t < 64; ++t) {
        s8v hi0, hi1, lo0, lo1;
        #pragma unroll
        for (int e = 0; e < 4; ++e) {
            float v;
            short h;
            v = cur0[e]; h = f2bf(v); hi0[e]     = h; lo0[e]     = f2bf(v - bf2f(h));
            v = cur1[e]; h = f2bf(v); hi0[e + 4] = h; lo0[e + 4] = f2bf(v - bf2f(h));
            v = cur2[e]; h = f2bf(v); hi1[e]     = h; lo1[e]     = f2bf(v - bf2f(h));
            v = cur3[e]; h = f2bf(v); hi1[e + 4] = h; lo1[e + 4] = f2bf(v - bf2f(h));
        }
        __syncthreads();
        *(s8v*)&awr[pw0] = hi0;
        *(s8v*)&awr[pw1] = hi1;
        *(s8v*)&awr[pw2] = lo0;
        *(s8v*)&awr[pw3] = lo1;
        {
            const short* bt = bP + (size_t)t * 32768;
            gload_lds16(bt,          bD);
            gload_lds16(bt +  512,   bD + 512);
            gload_lds16(bt + 1024,   bD + 1024);
            gload_lds16(bt + 1536,   bD + 1536);
        }
        if (t < 63) {
            const float* p = xP + (t + 1) * 32;
            cur0 = *(const f4v*)(p + 0);
            cur1 = *(const f4v*)(p + 4);
            cur2 = *(const f4v*)(p + 8);
            cur3 = *(const f4v*)(p + 12);
        }
        __syncthreads();

        #pragma unroll
        for (int ks = 0; ks < 2; ++ks) {
            const int ph0 = ks * 2 + (l >> 5);
            s8v ahf[2], alf[2], bhf[2], blf[2];
            #pragma unroll
            for (int m = 0; m < 2; ++m) {
                const int row = wr * 64 + m * 32 + (l & 31);
                const int ph = ph0 ^ (row & 7);
                ahf[m] = *(const s8v*)&Ab[row * 64 + ph * 8];
                alf[m] = *(const s8v*)&Ab[row * 64 + (ph ^ 4) * 8];
            }
            #pragma unroll
            for (int n = 0; n < 2; ++n) {
                const int col = wc * 64 + n * 32 + (l & 31);
                const int ph = ph0 ^ (col & 7);
                bhf[n] = *(const s8v*)&Bb[col * 64 + ph * 8];
                blf[n] = *(const s8v*)&Bb[col * 64 + (ph ^ 4) * 8];
            }
            #pragma unroll
            for (int m = 0; m < 2; ++m)
                #pragma unroll
                for (int n = 0; n < 2; ++n) {
                    acc[m][n] = __builtin_amdgcn_mfma_f32_32x32x16_bf16(ahf[m], bhf[n], acc[m][n], 0, 0, 0);
                    acc[m][n] = __builtin_amdgcn_mfma_f32_32x32x16_bf16(ahf[m], blf[n], acc[m][n], 0, 0, 0);
                    acc[m][n] = __builtin_amdgcn_mfma_f32_32x32x16_bf16(alf[m], bhf[n], acc[m][n], 0, 0, 0);
                }
        }
    }

    #pragma unroll
    for (int m = 0; m < 2; ++m) {
        #pragma unroll
        for (int n = 0; n < 2; ++n) {
            const int gcol = n0 + wc * 64 + n * 32 + (l & 31);
            const float bv = bias[gcol];
            #pragma unroll
            for (int r = 0; r < 16; ++r) {
                const int grow = m0 + wr * 64 + m * 32
                               + (r & 3) + 8 * (r >> 2) + 4 * (l >> 5);
                out[(size_t)grow * 512 + gcol] = gelu_f(acc[m][n][r] + bv);
            }
        }
    }
}

// ---------------------------------------------------------------------------
// Fused weight split (tail weights): W (K x N f32) -> [2][N][Kpad] bf16 planes.
// ---------------------------------------------------------------------------
struct SplitDesc { const float* W; short* dst; int K, N, Kpad, blk0; };
struct SplitPack { SplitDesc d[9]; };

__global__ void split_all(SplitPack p) {
    const int bid = blockIdx.x;
    int i = 0;
    #pragma unroll
    for (int j = 1; j < 9; ++j) if (bid >= p.d[j].blk0) i = j;
    const SplitDesc& D = p.d[i];
    const int idx = (bid - D.blk0) * 256 + threadIdx.x;
    const int total = D.N * D.Kpad;
    if (idx >= total) return;
    const int n = idx / D.Kpad, k = idx - n * D.Kpad;
    const float v = (k < D.K) ? D.W[(size_t)k * D.N + n] : 0.0f;
    const short hs = f2bf(v);
    D.dst[idx] = hs;
    D.dst[total + idx] = f2bf(v - bf2f(hs));
}

// ---------------------------------------------------------------------------
// levelk: F = (gelu(X @ Wa + ba)) @ Wb + bb   (DIN -> 128 -> 128)
// BM=64 rows/block, 512 blocks, 4 waves 2x2 (wave tile 32x64).
// Phase 1: K=DIN loop, A from global f32 (fused hi/lo cvt), B=Wa planes.
// g = gelu(...) stored f32 in LDS [64][132]. Phase 2: K=128 from g, B=Wb.
// ---------------------------------------------------------------------------
template<int DIN, int OSTR>
__launch_bounds__(256, 2)
__global__ void levelk(const float* __restrict__ X,
                       const short* __restrict__ Wa, const float* __restrict__ ba,
                       const short* __restrict__ Wb, const float* __restrict__ bb,
                       float* __restrict__ F)
{
    constexpr int NT1 = DIN / 32;
    __shared__ short stepb[(64 + 128) * 64];   // A 4096 + B 8192 shorts (24KB)
    __shared__ float gb[64 * 132];             // 33.8KB
    short* Ab = stepb;
    short* Bb = stepb + 64 * 64;

    const int tid = threadIdx.x;
    const int l = tid & 63, wid = tid >> 6;
    const int wr = wid >> 1, wc = wid & 1;
    const int m0 = blockIdx.x * 64;

    const int ar = tid >> 2, aseg = tid & 3;
    short* aw = Ab + ar * 64;
    const int ps0 = ((aseg    ) ^ (ar & 7)) * 8;
    const int ps1 = ((aseg + 4) ^ (ar & 7)) * 8;

    // B-source involution mapping (proven)
    const int cs = (l & 7) ^ (l >> 3);
    const int bplane = cs >> 2, kslot = cs & 3;

    f16v acc[2];
    acc[0] = (f16v)0.0f; acc[1] = (f16v)0.0f;

    auto computeStep = [&]() {
        #pragma unroll
        for (int ks = 0; ks < 2; ++ks) {
            const int c0 = ks * 2 + (l >> 5);
            const int row = wr * 32 + (l & 31);
            const int pa = c0 ^ (row & 7);
            s8v ah = *(const s8v*)&Ab[row * 64 + pa * 8];
            s8v al = *(const s8v*)&Ab[row * 64 + (pa ^ 4) * 8];
            #pragma unroll
            for (int n = 0; n < 2; ++n) {
                const int col = wc * 64 + n * 32 + (l & 31);
                const int pb = c0 ^ (col & 7);
                s8v bh = *(const s8v*)&Bb[col * 64 + pb * 8];
                s8v bl = *(const s8v*)&Bb[col * 64 + (pb ^ 4) * 8];
                acc[n] = __builtin_amdgcn_mfma_f32_32x32x16_bf16(ah, bh, acc[n], 0, 0, 0);
                acc[n] = __builtin_amdgcn_mfma_f32_32x32x16_bf16(ah, bl, acc[n], 0, 0, 0);
                acc[n] = __builtin_amdgcn_mfma_f32_32x32x16_bf16(al, bh, acc[n], 0, 0, 0);
            }
        }
    };
    auto cvt = [&](const f4v& u, const f4v& w, s8v& hi, s8v& lo) {
        #pragma unroll
        for (int e = 0; e < 4; ++e) {
            short h;
            h = f2bf(u[e]); hi[e]     = h; lo[e]     = f2bf(u[e] - bf2f(h));
            h = f2bf(w[e]); hi[e + 4] = h; lo[e + 4] = f2bf(w[e] - bf2f(h));
        }
    };

    // ---- phase 1: K = DIN ----
    {
        const float* xP = X + (size_t)(m0 + ar) * DIN + aseg * 8;
        f4v cA = *(const f4v*)(xP);
        f4v cB = *(const f4v*)(xP + 4);
        for (int t = 0; t < NT1; ++t) {
            s8v hi, lo; cvt(cA, cB, hi, lo);
            __syncthreads();
            *(s8v*)&aw[ps0] = hi;
            *(s8v*)&aw[ps1] = lo;
            #pragma unroll
            for (int j = 0; j < 4; ++j) {
                const int col = (wid * 4 + j) * 8 + (l >> 3);
                gload_lds16(Wa + (size_t)bplane * (128 * DIN) + (size_t)col * DIN
                               + t * 32 + kslot * 8,
                            Bb + (wid * 4 + j) * 512);
            }
            if (t + 1 < NT1) {
                const float* p = xP + (t + 1) * 32;
                cA = *(const f4v*)(p);
                cB = *(const f4v*)(p + 4);
            }
            __syncthreads();
            computeStep();
        }
    }

    // ---- gelu -> gb (f32) ----
    #pragma unroll
    for (int n = 0; n < 2; ++n) {
        const int col = wc * 64 + n * 32 + (l & 31);
        const float bv = ba[col];
        #pragma unroll
        for (int r = 0; r < 16; ++r) {
            const int row = wr * 32 + (r & 3) + 8 * (r >> 2) + 4 * (l >> 5);
            gb[row * 132 + col] = gelu_f(acc[n][r] + bv);
        }
    }
    acc[0] = (f16v)0.0f; acc[1] = (f16v)0.0f;
    __syncthreads();                           // gb complete before phase 2 reads

    // ---- phase 2: K = 128 from gb ----
    {
        const float* gP = gb + ar * 132 + aseg * 8;
        f4v cA = *(const f4v*)(gP);
        f4v cB = *(const f4v*)(gP + 4);
        for (int t = 0; t < 4; ++t) {
            s8v hi, lo; cvt(cA, cB, hi, lo);
            __syncthreads();
            *(s8v*)&aw[ps0] = hi;
            *(s8v*)&aw[ps1] = lo;
            #pragma unroll
            for (int j = 0; j < 4; ++j) {
                const int col = (wid * 4 + j) * 8 + (l >> 3);
                gload_lds16(Wb + (size_t)bplane * (128 * 128) + (size_t)col * 128
                               + t * 32 + kslot * 8,
                            Bb + (wid * 4 + j) * 512);
            }
            if (t + 1 < 4) {
                const float* p = gP + (t + 1) * 32;
                cA = *(const f4v*)(p);
                cB = *(const f4v*)(p + 4);
            }
            __syncthreads();
            computeStep();
        }
    }

    // ---- epilogue: F = acc + bb ----
    #pragma unroll
    for (int n = 0; n < 2; ++n) {
        const int col = wc * 64 + n * 32 + (l & 31);
        const float bv = bb[col];
        #pragma unroll
        for (int r = 0; r < 16; ++r) {
            const int row = wr * 32 + (r & 3) + 8 * (r >> 2) + 4 * (l >> 5);
            F[(size_t)(m0 + row) * OSTR + col] = acc[n][r] + bv;
        }
    }
}

// ---------------------------------------------------------------------------
// Tail GEMM: bf16x3, 32x32x16, BK=32, dbuf LDS, 2-phase prefetch.
// EPI: 0 = +bias,gelu ; 1 = +bias ; 2 = softmax64+argmax ; 3 = LayerNorm(256).
// ---------------------------------------------------------------------------
template<int BM, int BN, int EPI>
__launch_bounds__(256, 2)
__global__ void gemm32(const float* __restrict__ A, int lda,
                       const short* __restrict__ Bsp, int ldb, int NK,
                       const float* __restrict__ bias, int K, int N, int ntiles,
                       float* __restrict__ out, float* __restrict__ out2,
                       const float* __restrict__ lng, const float* __restrict__ lnb)
{
    constexpr int MF  = BM / 64;
    constexpr int NFw = BN / 64;
    constexpr int BUF = (BM + BN) * 64;
    constexpr int FPT = BM / 8;
    constexpr int TPR = 32 / FPT;
    constexpr int nBI = BN / 32;
    __shared__ short smem[2 * BUF];

    const int tid = threadIdx.x;
    const int l   = tid & 63, wid = tid >> 6;
    const int wr  = wid >> 1, wc = wid & 1;
    const int bid = blockIdx.x;
    const int ntb = bid % ntiles, mtb = bid / ntiles;
    const int m0  = mtb * BM, n0 = ntb * BN;

    const int ar = tid / TPR, aseg = tid % TPR;
    const float* aP = A + (size_t)(m0 + ar) * lda + aseg * FPT;

    const short* bg[nBI];
    {
        const int cs = (l & 7) ^ (l >> 3);
        const int plane = cs >> 2, kslot = cs & 3;
        #pragma unroll
        for (int j = 0; j < nBI; ++j) {
            const int col = (wid * nBI + j) * 8 + (l >> 3);
            bg[j] = Bsp + (size_t)plane * NK + (size_t)(n0 + col) * ldb + kslot * 8;
        }
    }

    f16v acc[MF][NFw];
    #pragma unroll
    for (int m = 0; m < MF; ++m)
        #pragma unroll
        for (int n = 0; n < NFw; ++n) acc[m][n] = (f16v)0.0f;

    f4v areg[FPT / 4];

    auto loadA = [&](int t) {
        const float* p = aP + t * 32;
        #pragma unroll
        for (int i = 0; i < FPT / 4; ++i) areg[i] = *(const f4v*)(p + i * 4);
    };
    auto stageB = [&](int t, short* buf) {
        short* Bb = buf + BM * 64;
        #pragma unroll
        for (int j = 0; j < nBI; ++j)
            gload_lds16(bg[j] + t * 32, Bb + (wid * nBI + j) * 512);
    };
    auto writeA = [&](short* buf) {
        #pragma unroll
        for (int c = 0; c < FPT / 8; ++c) {
            s8v hi, lo;
            #pragma unroll
            for (int e = 0; e < 8; ++e) {
                const float v = areg[c * 2 + (e >> 2)][e & 3];
                const short hs = f2bf(v);
                hi[e] = hs; lo[e] = f2bf(v - bf2f(hs));
            }
            const int csh = aseg * (FPT / 8) + c;
            *(s8v*)&buf[ar * 64 + ((csh    ) ^ (ar & 7)) * 8] = hi;
            *(s8v*)&buf[ar * 64 + ((csh + 4) ^ (ar & 7)) * 8] = lo;
        }
    };
    auto compute = [&](const short* buf) {
        const short* Ab = buf;
        const short* Bb = buf + BM * 64;
        #pragma unroll
        for (int ks = 0; ks < 2; ++ks) {
            const int csb = ks * 2 + (l >> 5);
            s8v ah[MF], al[MF], bh[NFw], bl[NFw];
            #pragma unroll
            for (int m = 0; m < MF; ++m) {
                const int row = wr * (BM / 2) + m * 32 + (l & 31);
                ah[m] = *(const s8v*)&Ab[row * 64 + ((csb    ) ^ (row & 7)) * 8];
                al[m] = *(const s8v*)&Ab[row * 64 + ((csb + 4) ^ (row & 7)) * 8];
            }
            #pragma unroll
            for (int n = 0; n < NFw; ++n) {
                const int col = wc * (BN / 2) + n * 32 + (l & 31);
                bh[n] = *(const s8v*)&Bb[col * 64 + ((csb    ) ^ (col & 7)) * 8];
                bl[n] = *(const s8v*)&Bb[col * 64 + ((csb + 4) ^ (col & 7)) * 8];
            }
            __builtin_amdgcn_s_setprio(1);
            #pragma unroll
            for (int m = 0; m < MF; ++m)
                #pragma unroll
                for (int n = 0; n < NFw; ++n) {
                    acc[m][n] = __builtin_amdgcn_mfma_f32_32x32x16_bf16(ah[m], bh[n], acc[m][n], 0, 0, 0);
                    acc[m][n] = __builtin_amdgcn_mfma_f32_32x32x16_bf16(ah[m], bl[n], acc[m][n], 0, 0, 0);
                    acc[m][n] = __builtin_amdgcn_mfma_f32_32x32x16_bf16(al[m], bh[n], acc[m][n], 0, 0, 0);
                }
            __builtin_amdgcn_s_setprio(0);
        }
    };

    const int NT = K / 32;
    loadA(0);
    stageB(0, smem);
    writeA(smem);
    __syncthreads();
    for (int t = 0; t < NT; ++t) {
        short* curb = smem + (t & 1) * BUF;
        short* nxtb = smem + ((t & 1) ^ 1) * BUF;
        const bool pf = (t + 1 < NT);
        if (pf) { loadA(t + 1); stageB(t + 1, nxtb); }
        compute(curb);
        if (pf) writeA(nxtb);
        __syncthreads();
    }

    if constexpr (EPI <= 1) {
        #pragma unroll
        for (int m = 0; m < MF; ++m) {
            #pragma unroll
            for (int n = 0; n < NFw; ++n) {
                const int gcol = n0 + wc * (BN / 2) + n * 32 + (l & 31);
                const float bv = bias[gcol];
                #pragma unroll
                for (int r = 0; r < 16; ++r) {
                    const int grow = m0 + wr * (BM / 2) + m * 32
                                   + (r & 3) + 8 * (r >> 2) + 4 * (l >> 5);
                    float xv = acc[m][n][r] + bv;
                    if constexpr (EPI == 0) xv = gelu_f(xv);
                    out[(size_t)grow * N + gcol] = xv;
                }
            }
        }
    } else if constexpr (EPI == 2) {
        float* LT = reinterpret_cast<float*>(smem);   // [64][64]
        const int gcolL = wc * 32 + (l & 31);
        const float bv = bias[gcolL];
        #pragma unroll
        for (int r = 0; r < 16; ++r) {
            const int row = wr * 32 + (r & 3) + 8 * (r >> 2) + 4 * (l >> 5);
            LT[row * 64 + gcolL] = acc[0][0][r] + bv;
        }
        __syncthreads();
        const int r = tid >> 2, q = tid & 3;
        const float* Lr = LT + r * 64 + q * 16;
        float mx = Lr[0];
        #pragma unroll
        for (int c = 1; c < 16; ++c) mx = fmaxf(mx, Lr[c]);
        mx = fmaxf(mx, __shfl_xor(mx, 1));
        mx = fmaxf(mx, __shfl_xor(mx, 2));
        float ev[16]; float s = 0.0f;
        #pragma unroll
        for (int c = 0; c < 16; ++c) { ev[c] = expf(Lr[c] - mx); s += ev[c]; }
        s += __shfl_xor(s, 1);
        s += __shfl_xor(s, 2);
        float pmax = -1.0f; int arg = 0;
        #pragma unroll
        for (int c = 0; c < 16; ++c) {
            const float pv = ev[c] / s;
            out[(size_t)(m0 + r) * 64 + q * 16 + c] = pv;
            if (pv > pmax) { pmax = pv; arg = q * 16 + c; }
        }
        #pragma unroll
        for (int off = 1; off <= 2; off <<= 1) {
            const float po = __shfl_xor(pmax, off);
            const int   ao = __shfl_xor(arg, off);
            if (po > pmax || (po == pmax && ao < arg)) { pmax = po; arg = ao; }
        }
        if (q == 0) out2[m0 + r] = (float)arg;
    } else {
        // EPI==3: LayerNorm over N=256 (BM=64, BN=256, ntiles=1)
        float* LT = reinterpret_cast<float*>(smem);   // [64][264] = 67.6KB <= 80KB
        #pragma unroll
        for (int n = 0; n < NFw; ++n) {
            const int col = wc * (BN / 2) + n * 32 + (l & 31);
            const float bv = bias[col];
            #pragma unroll
            for (int r = 0; r < 16; ++r) {
                const int row = wr * 32 + (r & 3) + 8 * (r >> 2) + 4 * (l >> 5);
                LT[row * 264 + col] = acc[0][n][r] + bv;
            }
        }
        __syncthreads();
        const int r = tid >> 2, q = tid & 3;
        const float* Lr = LT + r * 264 + q * 64;
        float s = 0.0f;
        #pragma unroll
        for (int i = 0; i < 64; ++i) s += Lr[i];
        s += __shfl_xor(s, 1);
        s += __shfl_xor(s, 2);
        const float mu = s * 0.00390625f;
        float qv = 0.0f;
        #pragma unroll
        for (int i = 0; i < 64; ++i) { const float dd = Lr[i] - mu; qv += dd * dd; }
        qv += __shfl_xor(qv, 1);
        qv += __shfl_xor(qv, 2);
        const float sc = 1.0f / sqrtf(qv * 0.00390625f + 1e-5f);
        #pragma unroll
        for (int i = 0; i < 64; ++i) {
            const int c = q * 64 + i;
            out[(size_t)(m0 + r) * 256 + c] = (Lr[i] - mu) * sc * lng[c] + lnb[c];
        }
    }
}

// ---------------------------------------------------------------------------
// Level head: pos/geo/softmax, one wave per row, f32 exact.
// Writes the 4 probs into Pout[row*160 + 0..3] (comb-strided).
// ---------------------------------------------------------------------------
__global__ __launch_bounds__(256) void p_kernel(
    const float* __restrict__ X, int din,
    const float* __restrict__ F, int fstr,
    const float* __restrict__ W3d, const float* __restrict__ b3d,
    const float* __restrict__ cc,
    const float* __restrict__ rW, const float* __restrict__ rb,
    float* __restrict__ Pout)
{
    const int row = blockIdx.x * 4 + (threadIdx.x >> 6);
    const int l   = threadIdx.x & 63;
    float px0 = 0.f, px1 = 0.f, px2 = 0.f;
    const int per = din >> 6;
    const float* xr = X + (size_t)row * din;
    for (int i = 0; i < per; ++i) {
        const int k = l + (i << 6);
        const float xv = xr[k];
        px0 += xv * W3d[k*3 + 0];
        px1 += xv * W3d[k*3 + 1];
        px2 += xv * W3d[k*3 + 2];
    }
    float g0 = 0.f, g1 = 0.f, g2 = 0.f, g3 = 0.f;
    const float* fr = F + (size_t)row * fstr;
    #pragma unroll
    for (int i = 0; i < 2; ++i) {
        const int k = l + (i << 6);
        const float fv = fr[k];
        g0 += fv * rW[k*4 + 0]; g1 += fv * rW[k*4 + 1];
        g2 += fv * rW[k*4 + 2]; g3 += fv * rW[k*4 + 3];
    }
    #pragma unroll
    for (int o = 32; o; o >>= 1) {
        px0 += __shfl_xor(px0, o); px1 += __shfl_xor(px1, o); px2 += __shfl_xor(px2, o);
        g0  += __shfl_xor(g0, o);  g1  += __shfl_xor(g1, o);
        g2  += __shfl_xor(g2, o);  g3  += __shfl_xor(g3, o);
    }
    if (l == 0) {
        const float pos0 = px0 + b3d[0], pos1 = px1 + b3d[1], pos2 = px2 + b3d[2];
        float lg[4];
        float mx = -1e30f;
        float gg[4] = {g0, g1, g2, g3};
        #pragma unroll
        for (int c = 0; c < 4; ++c) {
            float a = gg[c] + rb[c]
                    + pos0 * rW[512 + c] + pos1 * rW[516 + c] + pos2 * rW[520 + c];
            const float d0 = pos0 - cc[c*3 + 0];
            const float d1 = pos1 - cc[c*3 + 1];
            const float d2 = pos2 - cc[c*3 + 2];
            a += 0.5f * (-(d0*d0 + d1*d1 + d2*d2) / 2.00000001f);
            lg[c] = a;
            mx = fmaxf(mx, a);
        }
        const float e0 = expf(lg[0]-mx), e1 = expf(lg[1]-mx),
                    e2 = expf(lg[2]-mx), e3 = expf(lg[3]-mx);
        const float s = e0 + e1 + e2 + e3;
        float* pr = Pout + (size_t)row * 160;
        pr[0] = e0/s; pr[1] = e1/s; pr[2] = e2/s; pr[3] = e3/s;
    }
}

// ---------------------------------------------------------------------------
extern "C" void kernel_launch(void* const* d_in, const int* in_sizes, int n_in,
                              void* d_out, int out_size, void* d_ws, size_t ws_size,
                              hipStream_t stream)
{
    (void)in_sizes; (void)n_in; (void)out_size; (void)ws_size;

    const float* x    = (const float*)d_in[0];
    const float* ipW1 = (const float*)d_in[1];
    const float* ipb1 = (const float*)d_in[2];
    const float* ipW2 = (const float*)d_in[3];
    const float* ipb2 = (const float*)d_in[4];
    const float* ln_g = (const float*)d_in[5];
    const float* ln_b = (const float*)d_in[6];
    const float* W3d[3] = {(const float*)d_in[7],  (const float*)d_in[17], (const float*)d_in[27]};
    const float* b3d[3] = {(const float*)d_in[8],  (const float*)d_in[18], (const float*)d_in[28]};
    const float* cc[3]  = {(const float*)d_in[9],  (const float*)d_in[19], (const float*)d_in[29]};
    const float* f1W[3] = {(const float*)d_in[11], (const float*)d_in[21], (const float*)d_in[31]};
    const float* f1b[3] = {(const float*)d_in[12], (const float*)d_in[22], (const float*)d_in[32]};
    const float* f2W[3] = {(const float*)d_in[13], (const float*)d_in[23], (const float*)d_in[33]};
    const float* f2b[3] = {(const float*)d_in[14], (const float*)d_in[24], (const float*)d_in[34]};
    const float* rW[3]  = {(const float*)d_in[15], (const float*)d_in[25], (const float*)d_in[35]};
    const float* rb[3]  = {(const float*)d_in[16], (const float*)d_in[26], (const float*)d_in[36]};
    const float* ehW1 = (const float*)d_in[37];
    const float* ehb1 = (const float*)d_in[38];
    const float* ehW2 = (const float*)d_in[39];
    const float* ehb2 = (const float*)d_in[40];

    size_t off = 0;
    auto take = [&](size_t bytes) -> void* {
        void* p = (char*)d_ws + off;
        off += (bytes + 255) & ~(size_t)255;
        return p;
    };
    auto takeW = [&](int N, int Kpad) -> short* {
        return (short*)take((size_t)2 * N * Kpad * 2);
    };
    short* W1img = (short*)take((size_t)64 * 512 * 64 * 2);   // 4 MiB LDS-image
    short* W2s = takeW(256, 512);
    short* L1a = takeW(128, 256);
    short* L1b = takeW(128, 128);
    short* L2a = takeW(128, 128);
    short* L2b = takeW(128, 128);
    short* L3a = takeW(128, 128);
    short* L3b = takeW(128, 128);
    short* E1s = takeW(256, 160);
    short* E2s = takeW(64, 256);
    float* h1 = (float*)take((size_t)B_ROWS * 512 * 4);   // 64 MiB, reused below
    float* h2 = (float*)take((size_t)B_ROWS * 256 * 4);
    float* f1 = (float*)take((size_t)B_ROWS * 128 * 4);
    float* f2 = (float*)take((size_t)B_ROWS * 128 * 4);
    float* comb = h1;                                        // [B][160], h1 dead by then
    float* geh  = (float*)((char*)h1 + ((size_t)22 << 20));  // [B][256]

    // ---- weight pre-passes ----
    split_w1_img<<<(64 * 512 * 8) / 256, 256, 0, stream>>>(ipW1, W1img);
    SplitPack sp;
    int blk = 0;
    auto desc = [&](int i, const float* W, short* dst, int K, int N, int Kpad) {
        sp.d[i] = {W, dst, K, N, Kpad, blk};
        blk += (N * Kpad + 255) / 256;
    };
    desc(0, ipW2,   W2s,  512, 256,  512);
    desc(1, f1W[0], L1a,  256, 128,  256);
    desc(2, f2W[0], L1b,  128, 128,  128);
    desc(3, f1W[1], L2a,  128, 128,  128);
    desc(4, f2W[1], L2b,  128, 128,  128);
    desc(5, f1W[2], L3a,  128, 128,  128);
    desc(6, f2W[2], L3b,  128, 128,  128);
    desc(7, ehW1,   E1s,  140, 256,  160);
    desc(8, ehW2,   E2s,  256,  64,  256);
    split_all<<<blk, 256, 0, stream>>>(sp);

    const dim3 blkT(256);
    constexpr int MG64 = B_ROWS / 64;   // 512

    // input_proj: GEMM1 -> h1; GEMM2 (+fused LayerNorm) -> h2
    gemm1k<<<1024, blkT, 0, stream>>>(x, W1img, ipb1, h1);
    gemm32<64,256,3><<<MG64, blkT, 0, stream>>>(h1, 512, W2s, 512, 256*512, ipb2,
                                                512, 256, 1, h2, nullptr, ln_g, ln_b);

    // levels (fused gelu(x@Wa)@Wb), probs straight into comb
    levelk<256,128><<<MG64, blkT, 0, stream>>>(h2, L1a, f1b[0], L1b, f2b[0], f1);
    p_kernel<<<B_ROWS/4, 256, 0, stream>>>(h2, 256, f1, 128, W3d[0], b3d[0], cc[0], rW[0], rb[0], comb + 128);
    levelk<128,128><<<MG64, blkT, 0, stream>>>(f1, L2a, f1b[1], L2b, f2b[1], f2);
    p_kernel<<<B_ROWS/4, 256, 0, stream>>>(f1, 128, f2, 128, W3d[1], b3d[1], cc[1], rW[1], rb[1], comb + 132);
    levelk<128,160><<<MG64, blkT, 0, stream>>>(f2, L3a, f1b[2], L3b, f2b[2], comb);
    p_kernel<<<B_ROWS/4, 256, 0, stream>>>(f2, 128, comb, 160, W3d[2], b3d[2], cc[2], rW[2], rb[2], comb + 136);

    // expert head (comb cols 140-159 hit zero weight rows -> no zero-fill needed)
    gemm32<64,128,0><<<MG64*2, blkT, 0, stream>>>(comb, 160, E1s, 160, 256*160, ehb1,
                                                  160, 256, 2, geh, nullptr, nullptr, nullptr);
    gemm32<64,64,2><<<MG64, blkT, 0, stream>>>(geh, 256, E2s, 256, 64*256, ehb2,
                                               256, 64, 1, (float*)d_out,
                                               (float*)d_out + (size_t)B_ROWS * 64, nullptr, nullptr);
}

// Round 6
// 538.903 us; speedup vs baseline: 1.1332x; 1.0307x over previous
//
#include <hip/hip_runtime.h>
#include <hip/hip_bf16.h>
#include <cstdint>
#include <cstddef>

// ---------------------------------------------------------------------------
// EnhancedBVHRouter forward, MI355X/gfx950. Round 6.
// GEMM1: round-3 gemm1k (proven 288us). GEMM2+LN: round-3 forms.
// megatail: levels 1-3 + p-heads + EH1 fused in ONE kernel (LDS-resident,
// 64 rows/block, 2 blocks/CU). Only geh spills (EH2 needs K-relayout).
// EH2+softmax+argmax: round-3 gemm32<64,64,2>.
// ---------------------------------------------------------------------------

typedef short  s8v  __attribute__((ext_vector_type(8)));
typedef float  f4v  __attribute__((ext_vector_type(4)));
typedef float  f16v __attribute__((ext_vector_type(16)));
typedef unsigned int u32;

#define B_ROWS 32768

template<int N> struct IC { static constexpr int v = N; };

__device__ inline short f2bf(float x) {
    __hip_bfloat16 h = __float2bfloat16(x);
    return __builtin_bit_cast(short, h);
}
__device__ inline float bf2f(short s) {
    return __bfloat162float(__builtin_bit_cast(__hip_bfloat16, s));
}
__device__ inline float gelu_f(float x) {
    return 0.5f * x * (1.0f + erff(x * 0.70710678118654752440f));
}
__device__ inline void gload_lds16(const short* g, short* l) {
    __builtin_amdgcn_global_load_lds(
        (const __attribute__((address_space(1))) u32*)g,
        (__attribute__((address_space(3))) u32*)l, 16, 0, 0);
}

// ---------------------------------------------------------------------------
// W1 -> LDS-image (round-3 proven).
// ---------------------------------------------------------------------------
__global__ void split_w1_img(const float* __restrict__ W, short* __restrict__ img)
{
    const int idx = blockIdx.x * 256 + threadIdx.x;     // 64*512*8 total
    const int p = idx & 7;
    const int n = (idx >> 3) & 511;
    const int t = idx >> 12;
    const int cs = p ^ (n & 7);
    const int plane = cs >> 2, kc = cs & 3;
    const int kbase = t * 32 + kc * 8;
    s8v v8;
    #pragma unroll
    for (int e = 0; e < 8; ++e) {
        const float v = W[(size_t)(kbase + e) * 512 + n];
        const short h = f2bf(v);
        v8[e] = plane ? f2bf(v - bf2f(h)) : h;
    }
    *(s8v*)&img[(size_t)((t * 512 + n) * 64 + p * 8)] = v8;
}

// ---------------------------------------------------------------------------
// GEMM1 (round-3 proven, 288us).
// ---------------------------------------------------------------------------
__launch_bounds__(256, 4)
__global__ void gemm1k(const float* __restrict__ X,
                       const short* __restrict__ Bimg,
                       const float* __restrict__ bias,
                       float* __restrict__ out)
{
    __shared__ short smem[128 * 64 * 2];
    short* Ab = smem;
    short* Bb = smem + 128 * 64;

    const int tid = threadIdx.x;
    const int l = tid & 63, wid = tid >> 6;
    const int wr = wid >> 1, wc = wid & 1;

    const int d = blockIdx.x;                 // 1024 blocks
    const int xcd = d & 7;
    const int m0 = ((xcd & 1) * 128 + (d >> 3)) * 128;
    const int n0 = (xcd >> 1) * 128;

    const int ar = tid & 127, ah = tid >> 7;
    const float* xP = X + (size_t)(m0 + ar) * 2048 + ah * 16;
    short* awr = Ab + ar * 64;
    const int pw0 = ((ah * 2    ) ^ (ar & 7)) * 8;
    const int pw1 = ((ah * 2 + 1) ^ (ar & 7)) * 8;
    const int pw2 = ((ah * 2 + 4) ^ (ar & 7)) * 8;
    const int pw3 = ((ah * 2 + 5) ^ (ar & 7)) * 8;

    const short* bP = Bimg + (size_t)n0 * 64 + (size_t)(wid * 4) * 512 + (size_t)l * 8;
    short* bD = Bb + wid * 4 * 512;

    f16v acc[2][2];
    #pragma unroll
    for (int m = 0; m < 2; ++m)
        #pragma unroll
        for (int n = 0; n < 2; ++n) acc[m][n] = (f16v)0.0f;

    f4v cur0, cur1, cur2, cur3;
    cur0 = *(const f4v*)(xP + 0);
    cur1 = *(const f4v*)(xP + 4);
    cur2 = *(const f4v*)(xP + 8);
    cur3 = *(const f4v*)(xP + 12);

    for (int t = 0; t < 64; ++t) {
        s8v hi0, hi1, lo0, lo1;
        #pragma unroll
        for (int e = 0; e < 4; ++e) {
            float v;
            short h;
            v = cur0[e]; h = f2bf(v); hi0[e]     = h; lo0[e]     = f2bf(v - bf2f(h));
            v = cur1[e]; h = f2bf(v); hi0[e + 4] = h; lo0[e + 4] = f2bf(v - bf2f(h));
            v = cur2[e]; h = f2bf(v); hi1[e]     = h; lo1[e]     = f2bf(v - bf2f(h));
            v = cur3[e]; h = f2bf(v); hi1[e + 4] = h; lo1[e + 4] = f2bf(v - bf2f(h));
        }
        __syncthreads();
        *(s8v*)&awr[pw0] = hi0;
        *(s8v*)&awr[pw1] = hi1;
        *(s8v*)&awr[pw2] = lo0;
        *(s8v*)&awr[pw3] = lo1;
        {
            const short* bt = bP + (size_t)t * 32768;
            gload_lds16(bt,          bD);
            gload_lds16(bt +  512,   bD + 512);
            gload_lds16(bt + 1024,   bD + 1024);
            gload_lds16(bt + 1536,   bD + 1536);
        }
        if (t < 63) {
            const float* p = xP + (t + 1) * 32;
            cur0 = *(const f4v*)(p + 0);
            cur1 = *(const f4v*)(p + 4);
            cur2 = *(const f4v*)(p + 8);
            cur3 = *(const f4v*)(p + 12);
        }
        __syncthreads();

        #pragma unroll
        for (int ks = 0; ks < 2; ++ks) {
            const int ph0 = ks * 2 + (l >> 5);
            s8v ahf[2], alf[2], bhf[2], blf[2];
            #pragma unroll
            for (int m = 0; m < 2; ++m) {
                const int row = wr * 64 + m * 32 + (l & 31);
                const int ph = ph0 ^ (row & 7);
                ahf[m] = *(const s8v*)&Ab[row * 64 + ph * 8];
                alf[m] = *(const s8v*)&Ab[row * 64 + (ph ^ 4) * 8];
            }
            #pragma unroll
            for (int n = 0; n < 2; ++n) {
                const int col = wc * 64 + n * 32 + (l & 31);
                const int ph = ph0 ^ (col & 7);
                bhf[n] = *(const s8v*)&Bb[col * 64 + ph * 8];
                blf[n] = *(const s8v*)&Bb[col * 64 + (ph ^ 4) * 8];
            }
            #pragma unroll
            for (int m = 0; m < 2; ++m)
                #pragma unroll
                for (int n = 0; n < 2; ++n) {
                    acc[m][n] = __builtin_amdgcn_mfma_f32_32x32x16_bf16(ahf[m], bhf[n], acc[m][n], 0, 0, 0);
                    acc[m][n] = __builtin_amdgcn_mfma_f32_32x32x16_bf16(ahf[m], blf[n], acc[m][n], 0, 0, 0);
                    acc[m][n] = __builtin_amdgcn_mfma_f32_32x32x16_bf16(alf[m], bhf[n], acc[m][n], 0, 0, 0);
                }
        }
    }

    #pragma unroll
    for (int m = 0; m < 2; ++m) {
        #pragma unroll
        for (int n = 0; n < 2; ++n) {
            const int gcol = n0 + wc * 64 + n * 32 + (l & 31);
            const float bv = bias[gcol];
            #pragma unroll
            for (int r = 0; r < 16; ++r) {
                const int grow = m0 + wr * 64 + m * 32
                               + (r & 3) + 8 * (r >> 2) + 4 * (l >> 5);
                out[(size_t)grow * 512 + gcol] = gelu_f(acc[m][n][r] + bv);
            }
        }
    }
}

// ---------------------------------------------------------------------------
// Weight split: W (K x N f32) -> [2][N][Kpad] bf16 planes.
// ---------------------------------------------------------------------------
struct SplitDesc { const float* W; short* dst; int K, N, Kpad, blk0; };
struct SplitPack { SplitDesc d[9]; };

__global__ void split_all(SplitPack p) {
    const int bid = blockIdx.x;
    int i = 0;
    #pragma unroll
    for (int j = 1; j < 9; ++j) if (bid >= p.d[j].blk0) i = j;
    const SplitDesc& D = p.d[i];
    const int idx = (bid - D.blk0) * 256 + threadIdx.x;
    const int total = D.N * D.Kpad;
    if (idx >= total) return;
    const int n = idx / D.Kpad, k = idx - n * D.Kpad;
    const float v = (k < D.K) ? D.W[(size_t)k * D.N + n] : 0.0f;
    const short hs = f2bf(v);
    D.dst[idx] = hs;
    D.dst[total + idx] = f2bf(v - bf2f(hs));
}

// ---------------------------------------------------------------------------
// gemm32 (round-3): bf16x3, dbuf LDS, 2-phase prefetch. EPI 0/1/2.
// ---------------------------------------------------------------------------
template<int BM, int BN, int EPI>
__launch_bounds__(256, 2)
__global__ void gemm32(const float* __restrict__ A, int lda,
                       const short* __restrict__ Bsp, int ldb, int NK,
                       const float* __restrict__ bias, int K, int N, int ntiles,
                       float* __restrict__ out, float* __restrict__ out2)
{
    constexpr int MF  = BM / 64;
    constexpr int NFw = BN / 64;
    constexpr int BUF = (BM + BN) * 64;
    constexpr int FPT = BM / 8;
    constexpr int TPR = 32 / FPT;
    constexpr int nBI = BN / 32;
    __shared__ short smem[2 * BUF];

    const int tid = threadIdx.x;
    const int l   = tid & 63, wid = tid >> 6;
    const int wr  = wid >> 1, wc = wid & 1;
    const int bid = blockIdx.x;
    const int ntb = bid % ntiles, mtb = bid / ntiles;
    const int m0  = mtb * BM, n0 = ntb * BN;

    const int ar = tid / TPR, aseg = tid % TPR;
    const float* aP = A + (size_t)(m0 + ar) * lda + aseg * FPT;

    const short* bg[nBI];
    {
        const int cs = (l & 7) ^ (l >> 3);
        const int plane = cs >> 2, kslot = cs & 3;
        #pragma unroll
        for (int j = 0; j < nBI; ++j) {
            const int col = (wid * nBI + j) * 8 + (l >> 3);
            bg[j] = Bsp + (size_t)plane * NK + (size_t)(n0 + col) * ldb + kslot * 8;
        }
    }

    f16v acc[MF][NFw];
    #pragma unroll
    for (int m = 0; m < MF; ++m)
        #pragma unroll
        for (int n = 0; n < NFw; ++n) acc[m][n] = (f16v)0.0f;

    f4v areg[FPT / 4];

    auto loadA = [&](int t) {
        const float* p = aP + t * 32;
        #pragma unroll
        for (int i = 0; i < FPT / 4; ++i) areg[i] = *(const f4v*)(p + i * 4);
    };
    auto stageB = [&](int t, short* buf) {
        short* Bb = buf + BM * 64;
        #pragma unroll
        for (int j = 0; j < nBI; ++j)
            gload_lds16(bg[j] + t * 32, Bb + (wid * nBI + j) * 512);
    };
    auto writeA = [&](short* buf) {
        #pragma unroll
        for (int c = 0; c < FPT / 8; ++c) {
            s8v hi, lo;
            #pragma unroll
            for (int e = 0; e < 8; ++e) {
                const float v = areg[c * 2 + (e >> 2)][e & 3];
                const short hs = f2bf(v);
                hi[e] = hs; lo[e] = f2bf(v - bf2f(hs));
            }
            const int csh = aseg * (FPT / 8) + c;
            *(s8v*)&buf[ar * 64 + ((csh    ) ^ (ar & 7)) * 8] = hi;
            *(s8v*)&buf[ar * 64 + ((csh + 4) ^ (ar & 7)) * 8] = lo;
        }
    };
    auto compute = [&](const short* buf) {
        const short* Ab = buf;
        const short* Bb = buf + BM * 64;
        #pragma unroll
        for (int ks = 0; ks < 2; ++ks) {
            const int csb = ks * 2 + (l >> 5);
            s8v ah[MF], al[MF], bh[NFw], bl[NFw];
            #pragma unroll
            for (int m = 0; m < MF; ++m) {
                const int row = wr * (BM / 2) + m * 32 + (l & 31);
                ah[m] = *(const s8v*)&Ab[row * 64 + ((csb    ) ^ (row & 7)) * 8];
                al[m] = *(const s8v*)&Ab[row * 64 + ((csb + 4) ^ (row & 7)) * 8];
            }
            #pragma unroll
            for (int n = 0; n < NFw; ++n) {
                const int col = wc * (BN / 2) + n * 32 + (l & 31);
                bh[n] = *(const s8v*)&Bb[col * 64 + ((csb    ) ^ (col & 7)) * 8];
                bl[n] = *(const s8v*)&Bb[col * 64 + ((csb + 4) ^ (col & 7)) * 8];
            }
            __builtin_amdgcn_s_setprio(1);
            #pragma unroll
            for (int m = 0; m < MF; ++m)
                #pragma unroll
                for (int n = 0; n < NFw; ++n) {
                    acc[m][n] = __builtin_amdgcn_mfma_f32_32x32x16_bf16(ah[m], bh[n], acc[m][n], 0, 0, 0);
                    acc[m][n] = __builtin_amdgcn_mfma_f32_32x32x16_bf16(ah[m], bl[n], acc[m][n], 0, 0, 0);
                    acc[m][n] = __builtin_amdgcn_mfma_f32_32x32x16_bf16(al[m], bh[n], acc[m][n], 0, 0, 0);
                }
            __builtin_amdgcn_s_setprio(0);
        }
    };

    const int NT = K / 32;
    loadA(0);
    stageB(0, smem);
    writeA(smem);
    __syncthreads();
    for (int t = 0; t < NT; ++t) {
        short* curb = smem + (t & 1) * BUF;
        short* nxtb = smem + ((t & 1) ^ 1) * BUF;
        const bool pf = (t + 1 < NT);
        if (pf) { loadA(t + 1); stageB(t + 1, nxtb); }
        compute(curb);
        if (pf) writeA(nxtb);
        __syncthreads();
    }

    if constexpr (EPI <= 1) {
        #pragma unroll
        for (int m = 0; m < MF; ++m) {
            #pragma unroll
            for (int n = 0; n < NFw; ++n) {
                const int gcol = n0 + wc * (BN / 2) + n * 32 + (l & 31);
                const float bv = bias[gcol];
                #pragma unroll
                for (int r = 0; r < 16; ++r) {
                    const int grow = m0 + wr * (BM / 2) + m * 32
                                   + (r & 3) + 8 * (r >> 2) + 4 * (l >> 5);
                    float xv = acc[m][n][r] + bv;
                    if constexpr (EPI == 0) xv = gelu_f(xv);
                    out[(size_t)grow * N + gcol] = xv;
                }
            }
        }
    } else {
        float* LT = reinterpret_cast<float*>(smem);   // [64][64]
        const int gcolL = wc * 32 + (l & 31);
        const float bv = bias[gcolL];
        #pragma unroll
        for (int r = 0; r < 16; ++r) {
            const int row = wr * 32 + (r & 3) + 8 * (r >> 2) + 4 * (l >> 5);
            LT[row * 64 + gcolL] = acc[0][0][r] + bv;
        }
        __syncthreads();
        const int r = tid >> 2, q = tid & 3;
        const float* Lr = LT + r * 64 + q * 16;
        float mx = Lr[0];
        #pragma unroll
        for (int c = 1; c < 16; ++c) mx = fmaxf(mx, Lr[c]);
        mx = fmaxf(mx, __shfl_xor(mx, 1));
        mx = fmaxf(mx, __shfl_xor(mx, 2));
        float ev[16]; float s = 0.0f;
        #pragma unroll
        for (int c = 0; c < 16; ++c) { ev[c] = expf(Lr[c] - mx); s += ev[c]; }
        s += __shfl_xor(s, 1);
        s += __shfl_xor(s, 2);
        float pmax = -1.0f; int arg = 0;
        #pragma unroll
        for (int c = 0; c < 16; ++c) {
            const float pv = ev[c] / s;
            out[(size_t)(m0 + r) * 64 + q * 16 + c] = pv;
            if (pv > pmax) { pmax = pv; arg = q * 16 + c; }
        }
        #pragma unroll
        for (int off = 1; off <= 2; off <<= 1) {
            const float po = __shfl_xor(pmax, off);
            const int   ao = __shfl_xor(arg, off);
            if (po > pmax || (po == pmax && ao < arg)) { pmax = po; arg = ao; }
        }
        if (q == 0) out2[m0 + r] = (float)arg;
    }
}

// ---------------------------------------------------------------------------
// LayerNorm(256) in place (round-3).
// ---------------------------------------------------------------------------
__global__ __launch_bounds__(256) void ln_kernel(float* __restrict__ H,
                                                 const float* __restrict__ G,
                                                 const float* __restrict__ Bv)
{
    const int row = blockIdx.x * 4 + (threadIdx.x >> 6);
    const int l   = threadIdx.x & 63;
    float* hr = H + (size_t)row * 256;
    f4v v = *reinterpret_cast<const f4v*>(&hr[l * 4]);
    float s = v[0] + v[1] + v[2] + v[3];
    #pragma unroll
    for (int o = 32; o; o >>= 1) s += __shfl_xor(s, o);
    const float mu = s * 0.00390625f;
    f4v d = v - mu;
    float q = d[0]*d[0] + d[1]*d[1] + d[2]*d[2] + d[3]*d[3];
    #pragma unroll
    for (int o = 32; o; o >>= 1) q += __shfl_xor(q, o);
    const float var = q * 0.00390625f;
    const float sc  = 1.0f / sqrtf(var + 1e-5f);
    f4v gg = *reinterpret_cast<const f4v*>(&G[l * 4]);
    f4v bb = *reinterpret_cast<const f4v*>(&Bv[l * 4]);
    f4v o4 = d * sc * gg + bb;
    *reinterpret_cast<f4v*>(&hr[l * 4]) = o4;
}

// ---------------------------------------------------------------------------
// megatail: per 64-row block: levels 1-3 (bf16x3 MFMA phases), p-heads (VALU),
// comb assembly, EH1 (2 n-halves) -> gelu -> geh (global).
// ---------------------------------------------------------------------------
struct TailArgs {
    const float* h2;
    const short* La[3]; const float* ba[3];
    const short* Lb[3]; const float* bb[3];
    const short* E1;    const float* eb1;
    const float* W3d[3]; const float* b3d[3]; const float* cc[3];
    const float* rW[3];  const float* rb[3];
    float* geh;
};

__launch_bounds__(256, 2)
__global__ void megatail(TailArgs A)
{
    __shared__ float Fbuf[64 * 164];    // 42KB: f_k / g / comb
    __shared__ short Astage[64 * 64];   // 8KB
    __shared__ short Bstage[128 * 64];  // 16KB (also f32 const scratch for p)
    __shared__ float pbuf[64 * 12];     // 3KB

    const int tid = threadIdx.x;
    const int l = tid & 63, wid = tid >> 6;
    const int wr = wid >> 1, wc = wid & 1;
    const int m0 = blockIdx.x * 64;

    const int ar = tid >> 2, aseg = tid & 3;
    short* aw = Astage + ar * 64;
    const int ps0 = ((aseg    ) ^ (ar & 7)) * 8;
    const int ps1 = ((aseg + 4) ^ (ar & 7)) * 8;

    const int cs = (l & 7) ^ (l >> 3);
    const int bplane = cs >> 2, kslot = cs & 3;

    f16v acc[2];

    auto accReset = [&]() { acc[0] = (f16v)0.0f; acc[1] = (f16v)0.0f; };

    auto computeStep = [&]() {
        #pragma unroll
        for (int ks = 0; ks < 2; ++ks) {
            const int c0 = ks * 2 + (l >> 5);
            const int row = wr * 32 + (l & 31);
            const int pa = c0 ^ (row & 7);
            s8v ah = *(const s8v*)&Astage[row * 64 + pa * 8];
            s8v al = *(const s8v*)&Astage[row * 64 + (pa ^ 4) * 8];
            #pragma unroll
            for (int n = 0; n < 2; ++n) {
                const int col = wc * 64 + n * 32 + (l & 31);
                const int pb = c0 ^ (col & 7);
                s8v bh = *(const s8v*)&Bstage[col * 64 + pb * 8];
                s8v bl = *(const s8v*)&Bstage[col * 64 + (pb ^ 4) * 8];
                acc[n] = __builtin_amdgcn_mfma_f32_32x32x16_bf16(ah, bh, acc[n], 0, 0, 0);
                acc[n] = __builtin_amdgcn_mfma_f32_32x32x16_bf16(ah, bl, acc[n], 0, 0, 0);
                acc[n] = __builtin_amdgcn_mfma_f32_32x32x16_bf16(al, bh, acc[n], 0, 0, 0);
            }
        }
    };
    auto cvt = [&](const f4v& u, const f4v& w, s8v& hi, s8v& lo) {
        #pragma unroll
        for (int e = 0; e < 4; ++e) {
            short h;
            h = f2bf(u[e]); hi[e]     = h; lo[e]     = f2bf(u[e] - bf2f(h));
            h = f2bf(w[e]); hi[e + 4] = h; lo[e + 4] = f2bf(w[e] - bf2f(h));
        }
    };
    auto stageBt = [&](const short* Bpl, int Kpad, int NKpl, int n0, int t) {
        #pragma unroll
        for (int j = 0; j < 4; ++j) {
            const int col = (wid * 4 + j) * 8 + (l >> 3);
            gload_lds16(Bpl + (size_t)bplane * NKpl + (size_t)(n0 + col) * Kpad
                            + t * 32 + kslot * 8,
                        Bstage + (wid * 4 + j) * 512);
        }
    };

    // phase with A from registers (xr: 2 f4v per t-step)
    auto phaseRegs = [&](auto NTc, const f4v* xr, const short* Bpl, int Kpad, int NKpl) {
        constexpr int NT = decltype(NTc)::v;
        #pragma unroll
        for (int t = 0; t < NT; ++t) {
            s8v hi, lo; cvt(xr[2 * t], xr[2 * t + 1], hi, lo);
            __syncthreads();
            *(s8v*)&aw[ps0] = hi;
            *(s8v*)&aw[ps1] = lo;
            stageBt(Bpl, Kpad, NKpl, 0, t);
            __syncthreads();
            computeStep();
        }
    };
    // phase with A from Fbuf (stride 164)
    auto phaseLDS = [&](auto NTc, const short* Bpl, int Kpad, int NKpl, int n0) {
        constexpr int NT = decltype(NTc)::v;
        f4v cA = *(const f4v*)&Fbuf[ar * 164 + aseg * 8];
        f4v cB = *(const f4v*)&Fbuf[ar * 164 + aseg * 8 + 4];
        #pragma unroll
        for (int t = 0; t < NT; ++t) {
            s8v hi, lo; cvt(cA, cB, hi, lo);
            __syncthreads();
            *(s8v*)&aw[ps0] = hi;
            *(s8v*)&aw[ps1] = lo;
            stageBt(Bpl, Kpad, NKpl, n0, t);
            if (t + 1 < NT) {
                cA = *(const f4v*)&Fbuf[ar * 164 + (t + 1) * 32 + aseg * 8];
                cB = *(const f4v*)&Fbuf[ar * 164 + (t + 1) * 32 + aseg * 8 + 4];
            }
            __syncthreads();
            computeStep();
        }
    };
    // epilogue: acc(+bias)(gelu?) -> Fbuf
    auto outEpi = [&](const float* bv_arr, bool dogelu) {
        #pragma unroll
        for (int n = 0; n < 2; ++n) {
            const int col = wc * 64 + n * 32 + (l & 31);
            const float bv = bv_arr[col];
            #pragma unroll
            for (int r = 0; r < 16; ++r) {
                const int row = wr * 32 + (r & 3) + 8 * (r >> 2) + 4 * (l >> 5);
                float xv = acc[n][r] + bv;
                if (dogelu) xv = gelu_f(xv);
                Fbuf[row * 164 + col] = xv;
            }
        }
    };
    // p-head: pos from input regs, feat from Fbuf, softmax4 -> pbuf
    auto pComp = [&](auto NSLc, const f4v* xr, const float* W3dG, const float* b3dG,
                     const float* ccG, const float* rWG, const float* rbG, int pidx) {
        constexpr int NSL = decltype(NSLc)::v;
        float* Cs = (float*)Bstage;
        __syncthreads();                       // Bstage free, Fbuf writes visible
        for (int i = tid; i < NSL * 32 * 3; i += 256) Cs[i] = W3dG[i];
        for (int i = tid; i < 131 * 4;      i += 256) Cs[1024 + i] = rWG[i];
        if (tid < 12) Cs[1600 + tid] = ccG[tid];
        if (tid < 3)  Cs[1616 + tid] = b3dG[tid];
        if (tid < 4)  Cs[1620 + tid] = rbG[tid];
        __syncthreads();
        float p0 = 0.f, p1 = 0.f, p2 = 0.f;
        #pragma unroll
        for (int t = 0; t < NSL; ++t)
            #pragma unroll
            for (int e = 0; e < 8; ++e) {
                const int k = t * 32 + aseg * 8 + e;
                const float v = (e < 4) ? xr[2 * t][e] : xr[2 * t + 1][e - 4];
                p0 += v * Cs[k * 3 + 0];
                p1 += v * Cs[k * 3 + 1];
                p2 += v * Cs[k * 3 + 2];
            }
        float g0 = 0.f, g1 = 0.f, g2 = 0.f, g3 = 0.f;
        #pragma unroll
        for (int i = 0; i < 32; ++i) {
            const int k = aseg * 32 + i;
            const float f = Fbuf[ar * 164 + k];
            g0 += f * Cs[1024 + k * 4 + 0];
            g1 += f * Cs[1024 + k * 4 + 1];
            g2 += f * Cs[1024 + k * 4 + 2];
            g3 += f * Cs[1024 + k * 4 + 3];
        }
        #pragma unroll
        for (int o = 1; o <= 2; o <<= 1) {
            p0 += __shfl_xor(p0, o); p1 += __shfl_xor(p1, o); p2 += __shfl_xor(p2, o);
            g0 += __shfl_xor(g0, o); g1 += __shfl_xor(g1, o);
            g2 += __shfl_xor(g2, o); g3 += __shfl_xor(g3, o);
        }
        if (aseg == 0) {
            const float pos0 = p0 + Cs[1616], pos1 = p1 + Cs[1617], pos2 = p2 + Cs[1618];
            float lg[4];
            float gg[4] = {g0, g1, g2, g3};
            float mx = -1e30f;
            #pragma unroll
            for (int c = 0; c < 4; ++c) {
                float a = gg[c] + Cs[1620 + c]
                        + pos0 * Cs[1024 + 128 * 4 + c]
                        + pos1 * Cs[1024 + 129 * 4 + c]
                        + pos2 * Cs[1024 + 130 * 4 + c];
                const float d0 = pos0 - Cs[1600 + c * 3 + 0];
                const float d1 = pos1 - Cs[1600 + c * 3 + 1];
                const float d2 = pos2 - Cs[1600 + c * 3 + 2];
                a += 0.5f * (-(d0 * d0 + d1 * d1 + d2 * d2) / 2.00000001f);
                lg[c] = a;
                mx = fmaxf(mx, a);
            }
            const float e0 = expf(lg[0] - mx), e1 = expf(lg[1] - mx),
                        e2 = expf(lg[2] - mx), e3 = expf(lg[3] - mx);
            const float s = e0 + e1 + e2 + e3;
            float* pr = pbuf + ar * 12 + pidx * 4;
            pr[0] = e0 / s; pr[1] = e1 / s; pr[2] = e2 / s; pr[3] = e3 / s;
        }
    };

    // ---- level 1 (din=256) ----
    f4v x1[16];
    {
        const float* xp = A.h2 + (size_t)(m0 + ar) * 256 + aseg * 8;
        #pragma unroll
        for (int t = 0; t < 8; ++t) {
            x1[2 * t]     = *(const f4v*)(xp + t * 32);
            x1[2 * t + 1] = *(const f4v*)(xp + t * 32 + 4);
        }
    }
    accReset();
    phaseRegs(IC<8>{}, x1, A.La[0], 256, 128 * 256);
    outEpi(A.ba[0], true);                 // g -> Fbuf
    accReset();
    __syncthreads();
    phaseLDS(IC<4>{}, A.Lb[0], 128, 128 * 128, 0);
    outEpi(A.bb[0], false);                // f1 -> Fbuf
    pComp(IC<8>{}, x1, A.W3d[0], A.b3d[0], A.cc[0], A.rW[0], A.rb[0], 0);

    // ---- level 2 ----
    f4v x2[8];
    #pragma unroll
    for (int t = 0; t < 4; ++t) {
        x2[2 * t]     = *(const f4v*)&Fbuf[ar * 164 + t * 32 + aseg * 8];
        x2[2 * t + 1] = *(const f4v*)&Fbuf[ar * 164 + t * 32 + aseg * 8 + 4];
    }
    accReset();
    phaseRegs(IC<4>{}, x2, A.La[1], 128, 128 * 128);
    outEpi(A.ba[1], true);
    accReset();
    __syncthreads();
    phaseLDS(IC<4>{}, A.Lb[1], 128, 128 * 128, 0);
    outEpi(A.bb[1], false);                // f2 -> Fbuf
    pComp(IC<4>{}, x2, A.W3d[1], A.b3d[1], A.cc[1], A.rW[1], A.rb[1], 1);

    // ---- level 3 ----
    f4v x3[8];
    #pragma unroll
    for (int t = 0; t < 4; ++t) {
        x3[2 * t]     = *(const f4v*)&Fbuf[ar * 164 + t * 32 + aseg * 8];
        x3[2 * t + 1] = *(const f4v*)&Fbuf[ar * 164 + t * 32 + aseg * 8 + 4];
    }
    accReset();
    phaseRegs(IC<4>{}, x3, A.La[2], 128, 128 * 128);
    outEpi(A.ba[2], true);
    accReset();
    __syncthreads();
    phaseLDS(IC<4>{}, A.Lb[2], 128, 128 * 128, 0);
    outEpi(A.bb[2], false);                // f3 -> Fbuf cols 0..127
    pComp(IC<4>{}, x3, A.W3d[2], A.b3d[2], A.cc[2], A.rW[2], A.rb[2], 2);

    // ---- assemble comb cols 128..163 ----
    __syncthreads();                       // pbuf complete
    {
        const int row = tid >> 2, base = (tid & 3) * 9;
        #pragma unroll
        for (int jj = 0; jj < 9; ++jj) {
            const int col = 128 + base + jj;
            Fbuf[row * 164 + col] = (col < 140) ? pbuf[row * 12 + (col - 128)] : 0.0f;
        }
    }
    __syncthreads();

    // ---- EH1: K=160, N=256 in two 128-col halves -> gelu -> geh ----
    #pragma unroll
    for (int nh = 0; nh < 2; ++nh) {
        accReset();
        phaseLDS(IC<5>{}, A.E1, 160, 256 * 160, nh * 128);
        #pragma unroll
        for (int n = 0; n < 2; ++n) {
            const int col = nh * 128 + wc * 64 + n * 32 + (l & 31);
            const float bv = A.eb1[col];
            #pragma unroll
            for (int r = 0; r < 16; ++r) {
                const int row = wr * 32 + (r & 3) + 8 * (r >> 2) + 4 * (l >> 5);
                A.geh[(size_t)(m0 + row) * 256 + col] = gelu_f(acc[n][r] + bv);
            }
        }
        if (nh == 0) __syncthreads();      // nh0 compute done before restaging
    }
}

// ---------------------------------------------------------------------------
extern "C" void kernel_launch(void* const* d_in, const int* in_sizes, int n_in,
                              void* d_out, int out_size, void* d_ws, size_t ws_size,
                              hipStream_t stream)
{
    (void)in_sizes; (void)n_in; (void)out_size; (void)ws_size;

    const float* x    = (const float*)d_in[0];
    const float* ipW1 = (const float*)d_in[1];
    const float* ipb1 = (const float*)d_in[2];
    const float* ipW2 = (const float*)d_in[3];
    const float* ipb2 = (const float*)d_in[4];
    const float* ln_g = (const float*)d_in[5];
    const float* ln_b = (const float*)d_in[6];
    const float* W3d[3] = {(const float*)d_in[7],  (const float*)d_in[17], (const float*)d_in[27]};
    const float* b3d[3] = {(const float*)d_in[8],  (const float*)d_in[18], (const float*)d_in[28]};
    const float* cc[3]  = {(const float*)d_in[9],  (const float*)d_in[19], (const float*)d_in[29]};
    const float* f1W[3] = {(const float*)d_in[11], (const float*)d_in[21], (const float*)d_in[31]};
    const float* f1b[3] = {(const float*)d_in[12], (const float*)d_in[22], (const float*)d_in[32]};
    const float* f2W[3] = {(const float*)d_in[13], (const float*)d_in[23], (const float*)d_in[33]};
    const float* f2b[3] = {(const float*)d_in[14], (const float*)d_in[24], (const float*)d_in[34]};
    const float* rW[3]  = {(const float*)d_in[15], (const float*)d_in[25], (const float*)d_in[35]};
    const float* rb[3]  = {(const float*)d_in[16], (const float*)d_in[26], (const float*)d_in[36]};
    const float* ehW1 = (const float*)d_in[37];
    const float* ehb1 = (const float*)d_in[38];
    const float* ehW2 = (const float*)d_in[39];
    const float* ehb2 = (const float*)d_in[40];

    size_t off = 0;
    auto take = [&](size_t bytes) -> void* {
        void* p = (char*)d_ws + off;
        off += (bytes + 255) & ~(size_t)255;
        return p;
    };
    auto takeW = [&](int N, int Kpad) -> short* {
        return (short*)take((size_t)2 * N * Kpad * 2);
    };
    short* W1img = (short*)take((size_t)64 * 512 * 64 * 2);   // 4 MiB
    short* W2s = takeW(256, 512);
    short* L1a = takeW(128, 256);
    short* L1b = takeW(128, 128);
    short* L2a = takeW(128, 128);
    short* L2b = takeW(128, 128);
    short* L3a = takeW(128, 128);
    short* L3b = takeW(128, 128);
    short* E1s = takeW(256, 160);
    short* E2s = takeW(64, 256);
    float* h1  = (float*)take((size_t)B_ROWS * 512 * 4);
    float* h2  = (float*)take((size_t)B_ROWS * 256 * 4);
    float* geh = (float*)take((size_t)B_ROWS * 256 * 4);

    // ---- weight pre-passes ----
    split_w1_img<<<(64 * 512 * 8) / 256, 256, 0, stream>>>(ipW1, W1img);
    SplitPack sp;
    int blk = 0;
    auto desc = [&](int i, const float* W, short* dst, int K, int N, int Kpad) {
        sp.d[i] = {W, dst, K, N, Kpad, blk};
        blk += (N * Kpad + 255) / 256;
    };
    desc(0, ipW2,   W2s,  512, 256,  512);
    desc(1, f1W[0], L1a,  256, 128,  256);
    desc(2, f2W[0], L1b,  128, 128,  128);
    desc(3, f1W[1], L2a,  128, 128,  128);
    desc(4, f2W[1], L2b,  128, 128,  128);
    desc(5, f1W[2], L3a,  128, 128,  128);
    desc(6, f2W[2], L3b,  128, 128,  128);
    desc(7, ehW1,   E1s,  140, 256,  160);
    desc(8, ehW2,   E2s,  256,  64,  256);
    split_all<<<blk, 256, 0, stream>>>(sp);

    const dim3 blkT(256);
    constexpr int MG64 = B_ROWS / 64;   // 512

    // input_proj
    gemm1k<<<1024, blkT, 0, stream>>>(x, W1img, ipb1, h1);
    gemm32<128,128,1><<<(B_ROWS/128)*2, blkT, 0, stream>>>(h1, 512, W2s, 512, 256*512,
                                                           ipb2, 512, 256, 2, h2, nullptr);
    ln_kernel<<<B_ROWS/4, 256, 0, stream>>>(h2, ln_g, ln_b);

    // fused tail: levels + p-heads + EH1
    TailArgs ta;
    ta.h2 = h2;
    ta.La[0] = L1a; ta.La[1] = L2a; ta.La[2] = L3a;
    ta.Lb[0] = L1b; ta.Lb[1] = L2b; ta.Lb[2] = L3b;
    ta.ba[0] = f1b[0]; ta.ba[1] = f1b[1]; ta.ba[2] = f1b[2];
    ta.bb[0] = f2b[0]; ta.bb[1] = f2b[1]; ta.bb[2] = f2b[2];
    ta.E1 = E1s; ta.eb1 = ehb1;
    for (int i = 0; i < 3; ++i) {
        ta.W3d[i] = W3d[i]; ta.b3d[i] = b3d[i]; ta.cc[i] = cc[i];
        ta.rW[i] = rW[i];   ta.rb[i] = rb[i];
    }
    ta.geh = geh;
    megatail<<<MG64, blkT, 0, stream>>>(ta);

    // EH2 + softmax + argmax
    gemm32<64,64,2><<<MG64, blkT, 0, stream>>>(geh, 256, E2s, 256, 64*256, ehb2,
                                               256, 64, 1, (float*)d_out,
                                               (float*)d_out + (size_t)B_ROWS * 64);
}

// Round 7
// 462.711 us; speedup vs baseline: 1.3198x; 1.1647x over previous
//
#include <hip/hip_runtime.h>
#include <hip/hip_bf16.h>
#include <cstdint>
#include <cstddef>

// ---------------------------------------------------------------------------
// EnhancedBVHRouter forward, MI355X/gfx950. Round 7.
// Base = round-3 (best known, 495us). Deltas:
//  - gemm1k: A-panel-sharing XCD swizzle (4 n-tiles of an m-panel co-resident
//    on one XCD -> A fetched once per panel; B-image goes L3-resident).
//  - gemm32: output-stride arg; L3b writes f3 straight into comb (stride 160),
//    concat deleted (stale cols 140-159 provably harmless: E1 pad rows = 0).
//  - p_all: the 3 level-heads in one launch (after L3b).
// ---------------------------------------------------------------------------

typedef short  s8v  __attribute__((ext_vector_type(8)));
typedef float  f4v  __attribute__((ext_vector_type(4)));
typedef float  f16v __attribute__((ext_vector_type(16)));
typedef unsigned int u32;

#define B_ROWS 32768

__device__ inline short f2bf(float x) {
    __hip_bfloat16 h = __float2bfloat16(x);
    return __builtin_bit_cast(short, h);
}
__device__ inline float bf2f(short s) {
    return __bfloat162float(__builtin_bit_cast(__hip_bfloat16, s));
}
__device__ inline float gelu_f(float x) {
    return 0.5f * x * (1.0f + erff(x * 0.70710678118654752440f));
}
__device__ inline void gload_lds16(const short* g, short* l) {
    __builtin_amdgcn_global_load_lds(
        (const __attribute__((address_space(1))) u32*)g,
        (__attribute__((address_space(3))) u32*)l, 16, 0, 0);
}

// ---------------------------------------------------------------------------
// W1 -> LDS-image (round-3 proven).
// ---------------------------------------------------------------------------
__global__ void split_w1_img(const float* __restrict__ W, short* __restrict__ img)
{
    const int idx = blockIdx.x * 256 + threadIdx.x;     // 64*512*8 total
    const int p = idx & 7;
    const int n = (idx >> 3) & 511;
    const int t = idx >> 12;
    const int cs = p ^ (n & 7);
    const int plane = cs >> 2, kc = cs & 3;
    const int kbase = t * 32 + kc * 8;
    s8v v8;
    #pragma unroll
    for (int e = 0; e < 8; ++e) {
        const float v = W[(size_t)(kbase + e) * 512 + n];
        const short h = f2bf(v);
        v8[e] = plane ? f2bf(v - bf2f(h)) : h;
    }
    *(s8v*)&img[(size_t)((t * 512 + n) * 64 + p * 8)] = v8;
}

// ---------------------------------------------------------------------------
// GEMM1 (round-3 structure; new A-panel-sharing XCD swizzle).
// ---------------------------------------------------------------------------
__launch_bounds__(256, 4)
__global__ void gemm1k(const float* __restrict__ X,
                       const short* __restrict__ Bimg,
                       const float* __restrict__ bias,
                       float* __restrict__ out)
{
    __shared__ short smem[128 * 64 * 2];
    short* Ab = smem;
    short* Bb = smem + 128 * 64;

    const int tid = threadIdx.x;
    const int l = tid & 63, wid = tid >> 6;
    const int wr = wid >> 1, wc = wid & 1;

    // A-panel-sharing swizzle: xcd = d&7 (HW round-robin), s = d>>3.
    // m-panel = xcd*32 + s>>2 (contiguous per XCD), n-tile = s&3:
    // the 4 n-blocks of a panel are co-resident on ONE XCD -> A 1x from HBM.
    const int d = blockIdx.x;                 // 1024 blocks
    const int xcd = d & 7, s = d >> 3;
    const int m0 = (xcd * 32 + (s >> 2)) * 128;
    const int n0 = (s & 3) * 128;

    const int ar = tid & 127, ah = tid >> 7;
    const float* xP = X + (size_t)(m0 + ar) * 2048 + ah * 16;
    short* awr = Ab + ar * 64;
    const int pw0 = ((ah * 2    ) ^ (ar & 7)) * 8;
    const int pw1 = ((ah * 2 + 1) ^ (ar & 7)) * 8;
    const int pw2 = ((ah * 2 + 4) ^ (ar & 7)) * 8;
    const int pw3 = ((ah * 2 + 5) ^ (ar & 7)) * 8;

    const short* bP = Bimg + (size_t)n0 * 64 + (size_t)(wid * 4) * 512 + (size_t)l * 8;
    short* bD = Bb + wid * 4 * 512;

    f16v acc[2][2];
    #pragma unroll
    for (int m = 0; m < 2; ++m)
        #pragma unroll
        for (int n = 0; n < 2; ++n) acc[m][n] = (f16v)0.0f;

    f4v cur0, cur1, cur2, cur3;
    cur0 = *(const f4v*)(xP + 0);
    cur1 = *(const f4v*)(xP + 4);
    cur2 = *(const f4v*)(xP + 8);
    cur3 = *(const f4v*)(xP + 12);

    for (int t = 0; t < 64; ++t) {
        s8v hi0, hi1, lo0, lo1;
        #pragma unroll
        for (int e = 0; e < 4; ++e) {
            float v;
            short h;
            v = cur0[e]; h = f2bf(v); hi0[e]     = h; lo0[e]     = f2bf(v - bf2f(h));
            v = cur1[e]; h = f2bf(v); hi0[e + 4] = h; lo0[e + 4] = f2bf(v - bf2f(h));
            v = cur2[e]; h = f2bf(v); hi1[e]     = h; lo1[e]     = f2bf(v - bf2f(h));
            v = cur3[e]; h = f2bf(v); hi1[e + 4] = h; lo1[e + 4] = f2bf(v - bf2f(h));
        }
        __syncthreads();
        *(s8v*)&awr[pw0] = hi0;
        *(s8v*)&awr[pw1] = hi1;
        *(s8v*)&awr[pw2] = lo0;
        *(s8v*)&awr[pw3] = lo1;
        {
            const short* bt = bP + (size_t)t * 32768;
            gload_lds16(bt,          bD);
            gload_lds16(bt +  512,   bD + 512);
            gload_lds16(bt + 1024,   bD + 1024);
            gload_lds16(bt + 1536,   bD + 1536);
        }
        if (t < 63) {
            const float* p = xP + (t + 1) * 32;
            cur0 = *(const f4v*)(p + 0);
            cur1 = *(const f4v*)(p + 4);
            cur2 = *(const f4v*)(p + 8);
            cur3 = *(const f4v*)(p + 12);
        }
        __syncthreads();

        #pragma unroll
        for (int ks = 0; ks < 2; ++ks) {
            const int ph0 = ks * 2 + (l >> 5);
            s8v ahf[2], alf[2], bhf[2], blf[2];
            #pragma unroll
            for (int m = 0; m < 2; ++m) {
                const int row = wr * 64 + m * 32 + (l & 31);
                const int ph = ph0 ^ (row & 7);
                ahf[m] = *(const s8v*)&Ab[row * 64 + ph * 8];
                alf[m] = *(const s8v*)&Ab[row * 64 + (ph ^ 4) * 8];
            }
            #pragma unroll
            for (int n = 0; n < 2; ++n) {
                const int col = wc * 64 + n * 32 + (l & 31);
                const int ph = ph0 ^ (col & 7);
                bhf[n] = *(const s8v*)&Bb[col * 64 + ph * 8];
                blf[n] = *(const s8v*)&Bb[col * 64 + (ph ^ 4) * 8];
            }
            #pragma unroll
            for (int m = 0; m < 2; ++m)
                #pragma unroll
                for (int n = 0; n < 2; ++n) {
                    acc[m][n] = __builtin_amdgcn_mfma_f32_32x32x16_bf16(ahf[m], bhf[n], acc[m][n], 0, 0, 0);
                    acc[m][n] = __builtin_amdgcn_mfma_f32_32x32x16_bf16(ahf[m], blf[n], acc[m][n], 0, 0, 0);
                    acc[m][n] = __builtin_amdgcn_mfma_f32_32x32x16_bf16(alf[m], bhf[n], acc[m][n], 0, 0, 0);
                }
        }
    }

    #pragma unroll
    for (int m = 0; m < 2; ++m) {
        #pragma unroll
        for (int n = 0; n < 2; ++n) {
            const int gcol = n0 + wc * 64 + n * 32 + (l & 31);
            const float bv = bias[gcol];
            #pragma unroll
            for (int r = 0; r < 16; ++r) {
                const int grow = m0 + wr * 64 + m * 32
                               + (r & 3) + 8 * (r >> 2) + 4 * (l >> 5);
                out[(size_t)grow * 512 + gcol] = gelu_f(acc[m][n][r] + bv);
            }
        }
    }
}

// ---------------------------------------------------------------------------
// Weight split: W (K x N f32) -> [2][N][Kpad] bf16 planes.
// ---------------------------------------------------------------------------
struct SplitDesc { const float* W; short* dst; int K, N, Kpad, blk0; };
struct SplitPack { SplitDesc d[9]; };

__global__ void split_all(SplitPack p) {
    const int bid = blockIdx.x;
    int i = 0;
    #pragma unroll
    for (int j = 1; j < 9; ++j) if (bid >= p.d[j].blk0) i = j;
    const SplitDesc& D = p.d[i];
    const int idx = (bid - D.blk0) * 256 + threadIdx.x;
    const int total = D.N * D.Kpad;
    if (idx >= total) return;
    const int n = idx / D.Kpad, k = idx - n * D.Kpad;
    const float v = (k < D.K) ? D.W[(size_t)k * D.N + n] : 0.0f;
    const short hs = f2bf(v);
    D.dst[idx] = hs;
    D.dst[total + idx] = f2bf(v - bf2f(hs));
}

// ---------------------------------------------------------------------------
// gemm32 (round-3 + output stride `ostr`): bf16x3, dbuf LDS, 2-phase prefetch.
// EPI: 0 = +bias,gelu ; 1 = +bias ; 2 = softmax64+argmax (ostr unused).
// ---------------------------------------------------------------------------
template<int BM, int BN, int EPI>
__launch_bounds__(256, 2)
__global__ void gemm32(const float* __restrict__ A, int lda,
                       const short* __restrict__ Bsp, int ldb, int NK,
                       const float* __restrict__ bias, int K, int N, int ntiles,
                       int ostr, float* __restrict__ out, float* __restrict__ out2)
{
    constexpr int MF  = BM / 64;
    constexpr int NFw = BN / 64;
    constexpr int BUF = (BM + BN) * 64;
    constexpr int FPT = BM / 8;
    constexpr int TPR = 32 / FPT;
    constexpr int nBI = BN / 32;
    __shared__ short smem[2 * BUF];

    const int tid = threadIdx.x;
    const int l   = tid & 63, wid = tid >> 6;
    const int wr  = wid >> 1, wc = wid & 1;
    const int bid = blockIdx.x;
    const int ntb = bid % ntiles, mtb = bid / ntiles;
    const int m0  = mtb * BM, n0 = ntb * BN;

    const int ar = tid / TPR, aseg = tid % TPR;
    const float* aP = A + (size_t)(m0 + ar) * lda + aseg * FPT;

    const short* bg[nBI];
    {
        const int cs = (l & 7) ^ (l >> 3);
        const int plane = cs >> 2, kslot = cs & 3;
        #pragma unroll
        for (int j = 0; j < nBI; ++j) {
            const int col = (wid * nBI + j) * 8 + (l >> 3);
            bg[j] = Bsp + (size_t)plane * NK + (size_t)(n0 + col) * ldb + kslot * 8;
        }
    }

    f16v acc[MF][NFw];
    #pragma unroll
    for (int m = 0; m < MF; ++m)
        #pragma unroll
        for (int n = 0; n < NFw; ++n) acc[m][n] = (f16v)0.0f;

    f4v areg[FPT / 4];

    auto loadA = [&](int t) {
        const float* p = aP + t * 32;
        #pragma unroll
        for (int i = 0; i < FPT / 4; ++i) areg[i] = *(const f4v*)(p + i * 4);
    };
    auto stageB = [&](int t, short* buf) {
        short* Bb = buf + BM * 64;
        #pragma unroll
        for (int j = 0; j < nBI; ++j)
            gload_lds16(bg[j] + t * 32, Bb + (wid * nBI + j) * 512);
    };
    auto writeA = [&](short* buf) {
        #pragma unroll
        for (int c = 0; c < FPT / 8; ++c) {
            s8v hi, lo;
            #pragma unroll
            for (int e = 0; e < 8; ++e) {
                const float v = areg[c * 2 + (e >> 2)][e & 3];
                const short hs = f2bf(v);
                hi[e] = hs; lo[e] = f2bf(v - bf2f(hs));
            }
            const int csh = aseg * (FPT / 8) + c;
            *(s8v*)&buf[ar * 64 + ((csh    ) ^ (ar & 7)) * 8] = hi;
            *(s8v*)&buf[ar * 64 + ((csh + 4) ^ (ar & 7)) * 8] = lo;
        }
    };
    auto compute = [&](const short* buf) {
        const short* Ab = buf;
        const short* Bb = buf + BM * 64;
        #pragma unroll
        for (int ks = 0; ks < 2; ++ks) {
            const int csb = ks * 2 + (l >> 5);
            s8v ah[MF], al[MF], bh[NFw], bl[NFw];
            #pragma unroll
            for (int m = 0; m < MF; ++m) {
                const int row = wr * (BM / 2) + m * 32 + (l & 31);
                ah[m] = *(const s8v*)&Ab[row * 64 + ((csb    ) ^ (row & 7)) * 8];
                al[m] = *(const s8v*)&Ab[row * 64 + ((csb + 4) ^ (row & 7)) * 8];
            }
            #pragma unroll
            for (int n = 0; n < NFw; ++n) {
                const int col = wc * (BN / 2) + n * 32 + (l & 31);
                bh[n] = *(const s8v*)&Bb[col * 64 + ((csb    ) ^ (col & 7)) * 8];
                bl[n] = *(const s8v*)&Bb[col * 64 + ((csb + 4) ^ (col & 7)) * 8];
            }
            __builtin_amdgcn_s_setprio(1);
            #pragma unroll
            for (int m = 0; m < MF; ++m)
                #pragma unroll
                for (int n = 0; n < NFw; ++n) {
                    acc[m][n] = __builtin_amdgcn_mfma_f32_32x32x16_bf16(ah[m], bh[n], acc[m][n], 0, 0, 0);
                    acc[m][n] = __builtin_amdgcn_mfma_f32_32x32x16_bf16(ah[m], bl[n], acc[m][n], 0, 0, 0);
                    acc[m][n] = __builtin_amdgcn_mfma_f32_32x32x16_bf16(al[m], bh[n], acc[m][n], 0, 0, 0);
                }
            __builtin_amdgcn_s_setprio(0);
        }
    };

    const int NT = K / 32;
    loadA(0);
    stageB(0, smem);
    writeA(smem);
    __syncthreads();
    for (int t = 0; t < NT; ++t) {
        short* curb = smem + (t & 1) * BUF;
        short* nxtb = smem + ((t & 1) ^ 1) * BUF;
        const bool pf = (t + 1 < NT);
        if (pf) { loadA(t + 1); stageB(t + 1, nxtb); }
        compute(curb);
        if (pf) writeA(nxtb);
        __syncthreads();
    }

    if constexpr (EPI <= 1) {
        #pragma unroll
        for (int m = 0; m < MF; ++m) {
            #pragma unroll
            for (int n = 0; n < NFw; ++n) {
                const int gcol = n0 + wc * (BN / 2) + n * 32 + (l & 31);
                const float bv = bias[gcol];
                #pragma unroll
                for (int r = 0; r < 16; ++r) {
                    const int grow = m0 + wr * (BM / 2) + m * 32
                                   + (r & 3) + 8 * (r >> 2) + 4 * (l >> 5);
                    float xv = acc[m][n][r] + bv;
                    if constexpr (EPI == 0) xv = gelu_f(xv);
                    out[(size_t)grow * ostr + gcol] = xv;
                }
            }
        }
    } else {
        float* LT = reinterpret_cast<float*>(smem);   // [64][64]
        const int gcolL = wc * 32 + (l & 31);
        const float bv = bias[gcolL];
        #pragma unroll
        for (int r = 0; r < 16; ++r) {
            const int row = wr * 32 + (r & 3) + 8 * (r >> 2) + 4 * (l >> 5);
            LT[row * 64 + gcolL] = acc[0][0][r] + bv;
        }
        __syncthreads();
        const int r = tid >> 2, q = tid & 3;
        const float* Lr = LT + r * 64 + q * 16;
        float mx = Lr[0];
        #pragma unroll
        for (int c = 1; c < 16; ++c) mx = fmaxf(mx, Lr[c]);
        mx = fmaxf(mx, __shfl_xor(mx, 1));
        mx = fmaxf(mx, __shfl_xor(mx, 2));
        float ev[16]; float s = 0.0f;
        #pragma unroll
        for (int c = 0; c < 16; ++c) { ev[c] = expf(Lr[c] - mx); s += ev[c]; }
        s += __shfl_xor(s, 1);
        s += __shfl_xor(s, 2);
        float pmax = -1.0f; int arg = 0;
        #pragma unroll
        for (int c = 0; c < 16; ++c) {
            const float pv = ev[c] / s;
            out[(size_t)(m0 + r) * 64 + q * 16 + c] = pv;
            if (pv > pmax) { pmax = pv; arg = q * 16 + c; }
        }
        #pragma unroll
        for (int off = 1; off <= 2; off <<= 1) {
            const float po = __shfl_xor(pmax, off);
            const int   ao = __shfl_xor(arg, off);
            if (po > pmax || (po == pmax && ao < arg)) { pmax = po; arg = ao; }
        }
        if (q == 0) out2[m0 + r] = (float)arg;
    }
}

// ---------------------------------------------------------------------------
// LayerNorm(256) in place (round-3).
// ---------------------------------------------------------------------------
__global__ __launch_bounds__(256) void ln_kernel(float* __restrict__ H,
                                                 const float* __restrict__ G,
                                                 const float* __restrict__ Bv)
{
    const int row = blockIdx.x * 4 + (threadIdx.x >> 6);
    const int l   = threadIdx.x & 63;
    float* hr = H + (size_t)row * 256;
    f4v v = *reinterpret_cast<const f4v*>(&hr[l * 4]);
    float s = v[0] + v[1] + v[2] + v[3];
    #pragma unroll
    for (int o = 32; o; o >>= 1) s += __shfl_xor(s, o);
    const float mu = s * 0.00390625f;
    f4v d = v - mu;
    float q = d[0]*d[0] + d[1]*d[1] + d[2]*d[2] + d[3]*d[3];
    #pragma unroll
    for (int o = 32; o; o >>= 1) q += __shfl_xor(q, o);
    const float var = q * 0.00390625f;
    const float sc  = 1.0f / sqrtf(var + 1e-5f);
    f4v gg = *reinterpret_cast<const f4v*>(&G[l * 4]);
    f4v bb = *reinterpret_cast<const f4v*>(&Bv[l * 4]);
    f4v o4 = d * sc * gg + bb;
    *reinterpret_cast<f4v*>(&hr[l * 4]) = o4;
}

// ---------------------------------------------------------------------------
// Level head (round-3 math) as device fn; p_all runs all 3 per wave.
// ---------------------------------------------------------------------------
__device__ void p_head(int row, int l,
                       const float* __restrict__ X, int din,
                       const float* __restrict__ F, int fstr,
                       const float* __restrict__ W3d, const float* __restrict__ b3d,
                       const float* __restrict__ cc,
                       const float* __restrict__ rW, const float* __restrict__ rb,
                       float* __restrict__ dst)
{
    float px0 = 0.f, px1 = 0.f, px2 = 0.f;
    const int per = din >> 6;
    const float* xr = X + (size_t)row * din;
    for (int i = 0; i < per; ++i) {
        const int k = l + (i << 6);
        const float xv = xr[k];
        px0 += xv * W3d[k*3 + 0];
        px1 += xv * W3d[k*3 + 1];
        px2 += xv * W3d[k*3 + 2];
    }
    float g0 = 0.f, g1 = 0.f, g2 = 0.f, g3 = 0.f;
    const float* fr = F + (size_t)row * fstr;
    #pragma unroll
    for (int i = 0; i < 2; ++i) {
        const int k = l + (i << 6);
        const float fv = fr[k];
        g0 += fv * rW[k*4 + 0]; g1 += fv * rW[k*4 + 1];
        g2 += fv * rW[k*4 + 2]; g3 += fv * rW[k*4 + 3];
    }
    #pragma unroll
    for (int o = 32; o; o >>= 1) {
        px0 += __shfl_xor(px0, o); px1 += __shfl_xor(px1, o); px2 += __shfl_xor(px2, o);
        g0  += __shfl_xor(g0, o);  g1  += __shfl_xor(g1, o);
        g2  += __shfl_xor(g2, o);  g3  += __shfl_xor(g3, o);
    }
    if (l == 0) {
        const float pos0 = px0 + b3d[0], pos1 = px1 + b3d[1], pos2 = px2 + b3d[2];
        float lg[4];
        float mx = -1e30f;
        float gg[4] = {g0, g1, g2, g3};
        #pragma unroll
        for (int c = 0; c < 4; ++c) {
            float a = gg[c] + rb[c]
                    + pos0 * rW[512 + c] + pos1 * rW[516 + c] + pos2 * rW[520 + c];
            const float d0 = pos0 - cc[c*3 + 0];
            const float d1 = pos1 - cc[c*3 + 1];
            const float d2 = pos2 - cc[c*3 + 2];
            a += 0.5f * (-(d0*d0 + d1*d1 + d2*d2) / 2.00000001f);
            lg[c] = a;
            mx = fmaxf(mx, a);
        }
        const float e0 = expf(lg[0]-mx), e1 = expf(lg[1]-mx),
                    e2 = expf(lg[2]-mx), e3 = expf(lg[3]-mx);
        const float s = e0 + e1 + e2 + e3;
        dst[0] = e0/s; dst[1] = e1/s; dst[2] = e2/s; dst[3] = e3/s;
    }
}

struct PAllArgs {
    const float* h2; const float* f1; const float* f2; float* comb;
    const float* W3d[3]; const float* b3d[3]; const float* cc[3];
    const float* rW[3];  const float* rb[3];
};

__global__ __launch_bounds__(256) void p_all(PAllArgs A)
{
    const int row = blockIdx.x * 4 + (threadIdx.x >> 6);
    const int l   = threadIdx.x & 63;
    float* cr = A.comb + (size_t)row * 160;
    p_head(row, l, A.h2, 256, A.f1,  128, A.W3d[0], A.b3d[0], A.cc[0], A.rW[0], A.rb[0], cr + 128);
    p_head(row, l, A.f1, 128, A.f2,  128, A.W3d[1], A.b3d[1], A.cc[1], A.rW[1], A.rb[1], cr + 132);
    p_head(row, l, A.f2, 128, A.comb, 160, A.W3d[2], A.b3d[2], A.cc[2], A.rW[2], A.rb[2], cr + 136);
}

// ---------------------------------------------------------------------------
extern "C" void kernel_launch(void* const* d_in, const int* in_sizes, int n_in,
                              void* d_out, int out_size, void* d_ws, size_t ws_size,
                              hipStream_t stream)
{
    (void)in_sizes; (void)n_in; (void)out_size; (void)ws_size;

    const float* x    = (const float*)d_in[0];
    const float* ipW1 = (const float*)d_in[1];
    const float* ipb1 = (const float*)d_in[2];
    const float* ipW2 = (const float*)d_in[3];
    const float* ipb2 = (const float*)d_in[4];
    const float* ln_g = (const float*)d_in[5];
    const float* ln_b = (const float*)d_in[6];
    const float* W3d[3] = {(const float*)d_in[7],  (const float*)d_in[17], (const float*)d_in[27]};
    const float* b3d[3] = {(const float*)d_in[8],  (const float*)d_in[18], (const float*)d_in[28]};
    const float* cc[3]  = {(const float*)d_in[9],  (const float*)d_in[19], (const float*)d_in[29]};
    const float* f1W[3] = {(const float*)d_in[11], (const float*)d_in[21], (const float*)d_in[31]};
    const float* f1b[3] = {(const float*)d_in[12], (const float*)d_in[22], (const float*)d_in[32]};
    const float* f2W[3] = {(const float*)d_in[13], (const float*)d_in[23], (const float*)d_in[33]};
    const float* f2b[3] = {(const float*)d_in[14], (const float*)d_in[24], (const float*)d_in[34]};
    const float* rW[3]  = {(const float*)d_in[15], (const float*)d_in[25], (const float*)d_in[35]};
    const float* rb[3]  = {(const float*)d_in[16], (const float*)d_in[26], (const float*)d_in[36]};
    const float* ehW1 = (const float*)d_in[37];
    const float* ehb1 = (const float*)d_in[38];
    const float* ehW2 = (const float*)d_in[39];
    const float* ehb2 = (const float*)d_in[40];

    size_t off = 0;
    auto take = [&](size_t bytes) -> void* {
        void* p = (char*)d_ws + off;
        off += (bytes + 255) & ~(size_t)255;
        return p;
    };
    auto takeW = [&](int N, int Kpad) -> short* {
        return (short*)take((size_t)2 * N * Kpad * 2);
    };
    short* W1img = (short*)take((size_t)64 * 512 * 64 * 2);   // 4 MiB
    short* W2s = takeW(256, 512);
    short* L1a = takeW(128, 256);
    short* L1b = takeW(128, 128);
    short* L2a = takeW(128, 128);
    short* L2b = takeW(128, 128);
    short* L3a = takeW(128, 128);
    short* L3b = takeW(128, 128);
    short* E1s = takeW(256, 160);
    short* E2s = takeW(64, 256);
    float* h1  = (float*)take((size_t)B_ROWS * 512 * 4);
    float* h2  = (float*)take((size_t)B_ROWS * 256 * 4);
    float* zg  = (float*)take((size_t)B_ROWS * 128 * 4);
    float* f1  = (float*)take((size_t)B_ROWS * 128 * 4);
    float* f2  = (float*)take((size_t)B_ROWS * 128 * 4);
    float* geh = (float*)take((size_t)B_ROWS * 256 * 4);
    float* comb = h1;                              // [B][160], h1 dead after gemm2

    // ---- weight pre-passes ----
    split_w1_img<<<(64 * 512 * 8) / 256, 256, 0, stream>>>(ipW1, W1img);
    SplitPack sp;
    int blk = 0;
    auto desc = [&](int i, const float* W, short* dst, int K, int N, int Kpad) {
        sp.d[i] = {W, dst, K, N, Kpad, blk};
        blk += (N * Kpad + 255) / 256;
    };
    desc(0, ipW2,   W2s,  512, 256,  512);
    desc(1, f1W[0], L1a,  256, 128,  256);
    desc(2, f2W[0], L1b,  128, 128,  128);
    desc(3, f1W[1], L2a,  128, 128,  128);
    desc(4, f2W[1], L2b,  128, 128,  128);
    desc(5, f1W[2], L3a,  128, 128,  128);
    desc(6, f2W[2], L3b,  128, 128,  128);
    desc(7, ehW1,   E1s,  140, 256,  160);
    desc(8, ehW2,   E2s,  256,  64,  256);
    split_all<<<blk, 256, 0, stream>>>(sp);

    const dim3 blkT(256);
    constexpr int MG128 = B_ROWS / 128;  // 256
    constexpr int MG64  = B_ROWS / 64;   // 512

    // input_proj
    gemm1k<<<1024, blkT, 0, stream>>>(x, W1img, ipb1, h1);
    gemm32<128,128,1><<<MG128*2, blkT, 0, stream>>>(h1, 512, W2s, 512, 256*512, ipb2,
                                                    512, 256, 2, 256, h2, nullptr);
    ln_kernel<<<B_ROWS/4, 256, 0, stream>>>(h2, ln_g, ln_b);

    // levels (gemm pairs; L3b writes f3 straight into comb at stride 160)
    gemm32<64,128,0><<<MG64, blkT, 0, stream>>>(h2, 256, L1a, 256, 128*256, f1b[0], 256, 128, 1, 128, zg, nullptr);
    gemm32<64,128,1><<<MG64, blkT, 0, stream>>>(zg, 128, L1b, 128, 128*128, f2b[0], 128, 128, 1, 128, f1, nullptr);
    gemm32<64,128,0><<<MG64, blkT, 0, stream>>>(f1, 128, L2a, 128, 128*128, f1b[1], 128, 128, 1, 128, zg, nullptr);
    gemm32<64,128,1><<<MG64, blkT, 0, stream>>>(zg, 128, L2b, 128, 128*128, f2b[1], 128, 128, 1, 128, f2, nullptr);
    gemm32<64,128,0><<<MG64, blkT, 0, stream>>>(f2, 128, L3a, 128, 128*128, f1b[2], 128, 128, 1, 128, zg, nullptr);
    gemm32<64,128,1><<<MG64, blkT, 0, stream>>>(zg, 128, L3b, 128, 128*128, f2b[2], 128, 128, 1, 160, comb, nullptr);

    // all three p-heads in one launch (inputs h2,f1,f2,comb all ready)
    PAllArgs pa;
    pa.h2 = h2; pa.f1 = f1; pa.f2 = f2; pa.comb = comb;
    for (int i = 0; i < 3; ++i) {
        pa.W3d[i] = W3d[i]; pa.b3d[i] = b3d[i]; pa.cc[i] = cc[i];
        pa.rW[i] = rW[i];   pa.rb[i] = rb[i];
    }
    p_all<<<B_ROWS/4, 256, 0, stream>>>(pa);

    // expert head (comb cols 140-159 stale but hit zero E1 pad rows)
    gemm32<64,128,0><<<MG64*2, blkT, 0, stream>>>(comb, 160, E1s, 160, 256*160, ehb1,
                                                  160, 256, 2, 256, geh, nullptr);
    gemm32<64,64,2><<<MG64, blkT, 0, stream>>>(geh, 256, E2s, 256, 64*256, ehb2,
                                               256, 64, 1, 64, (float*)d_out,
                                               (float*)d_out + (size_t)B_ROWS * 64);
}

// Round 8
// 460.225 us; speedup vs baseline: 1.3269x; 1.0054x over previous
//
#include <hip/hip_runtime.h>
#include <hip/hip_bf16.h>
#include <cstdint>
#include <cstddef>

// ---------------------------------------------------------------------------
// EnhancedBVHRouter forward, MI355X/gfx950. Round 8.
// Base = round-7 (best, 462us). Delta: gemm1k gets a B-double-buffered,
// raw-s_barrier pipeline with NO vmcnt drain in the loop: B-DMA(t+1) issued
// (older) then A-load(t+1) (newer); next iter's cvt waits on A regs, which by
// in-order vmem retirement also covers B — both hidden under compute(t).
// Only lgkmcnt(0) at the staging barrier. LDS 48KB -> 3 blocks/CU.
// Tail: round-7 unchanged.
// ---------------------------------------------------------------------------

typedef short  s8v  __attribute__((ext_vector_type(8)));
typedef float  f4v  __attribute__((ext_vector_type(4)));
typedef float  f16v __attribute__((ext_vector_type(16)));
typedef unsigned int u32;

#define B_ROWS 32768

__device__ inline short f2bf(float x) {
    __hip_bfloat16 h = __float2bfloat16(x);
    return __builtin_bit_cast(short, h);
}
__device__ inline float bf2f(short s) {
    return __bfloat162float(__builtin_bit_cast(__hip_bfloat16, s));
}
__device__ inline float gelu_f(float x) {
    return 0.5f * x * (1.0f + erff(x * 0.70710678118654752440f));
}
__device__ inline void gload_lds16(const short* g, short* l) {
    __builtin_amdgcn_global_load_lds(
        (const __attribute__((address_space(1))) u32*)g,
        (__attribute__((address_space(3))) u32*)l, 16, 0, 0);
}

// ---------------------------------------------------------------------------
// W1 -> LDS-image (round-3 proven).
// ---------------------------------------------------------------------------
__global__ void split_w1_img(const float* __restrict__ W, short* __restrict__ img)
{
    const int idx = blockIdx.x * 256 + threadIdx.x;     // 64*512*8 total
    const int p = idx & 7;
    const int n = (idx >> 3) & 511;
    const int t = idx >> 12;
    const int cs = p ^ (n & 7);
    const int plane = cs >> 2, kc = cs & 3;
    const int kbase = t * 32 + kc * 8;
    s8v v8;
    #pragma unroll
    for (int e = 0; e < 8; ++e) {
        const float v = W[(size_t)(kbase + e) * 512 + n];
        const short h = f2bf(v);
        v8[e] = plane ? f2bf(v - bf2f(h)) : h;
    }
    *(s8v*)&img[(size_t)((t * 512 + n) * 64 + p * 8)] = v8;
}

// ---------------------------------------------------------------------------
// GEMM1: pipelined (B dbuf, raw barriers, no loop vmcnt drain).
// BM=128, BN=128, BK=32, 4 waves 2x2, A-panel-sharing XCD swizzle (round-7).
// ---------------------------------------------------------------------------
__launch_bounds__(256, 3)
__global__ void gemm1k(const float* __restrict__ X,
                       const short* __restrict__ Bimg,
                       const float* __restrict__ bias,
                       float* __restrict__ out)
{
    __shared__ short smem[128 * 64 * 3];      // Ab | Bb0 | Bb1 (48KB)
    short* Ab  = smem;
    short* Bb0 = smem + 128 * 64;
    short* Bb1 = smem + 128 * 64 * 2;

    const int tid = threadIdx.x;
    const int l = tid & 63, wid = tid >> 6;
    const int wr = wid >> 1, wc = wid & 1;

    // A-panel-sharing swizzle (round-7 proven: FETCH 538->192MB)
    const int d = blockIdx.x;                 // 1024 blocks
    const int xcd = d & 7, s = d >> 3;
    const int m0 = (xcd * 32 + (s >> 2)) * 128;
    const int n0 = (s & 3) * 128;

    const int ar = tid & 127, ah = tid >> 7;
    const float* xP = X + (size_t)(m0 + ar) * 2048 + ah * 16;
    short* awr = Ab + ar * 64;
    const int pw0 = ((ah * 2    ) ^ (ar & 7)) * 8;
    const int pw1 = ((ah * 2 + 1) ^ (ar & 7)) * 8;
    const int pw2 = ((ah * 2 + 4) ^ (ar & 7)) * 8;
    const int pw3 = ((ah * 2 + 5) ^ (ar & 7)) * 8;

    const short* bP = Bimg + (size_t)n0 * 64 + (size_t)(wid * 4) * 512 + (size_t)l * 8;
    const int bdo = wid * 4 * 512;

    f16v acc[2][2];
    #pragma unroll
    for (int m = 0; m < 2; ++m)
        #pragma unroll
        for (int n = 0; n < 2; ++n) acc[m][n] = (f16v)0.0f;

    f4v cur0, cur1, cur2, cur3;

    auto stageB = [&](int t, short* base) {
        const short* bt = bP + (size_t)t * 32768;
        short* bD = base + bdo;
        gload_lds16(bt,        bD);
        gload_lds16(bt +  512, bD + 512);
        gload_lds16(bt + 1024, bD + 1024);
        gload_lds16(bt + 1536, bD + 1536);
    };
    auto loadA = [&](int t) {
        const float* p = xP + t * 32;
        cur0 = *(const f4v*)(p + 0);
        cur1 = *(const f4v*)(p + 4);
        cur2 = *(const f4v*)(p + 8);
        cur3 = *(const f4v*)(p + 12);
    };
    auto compute = [&](const short* Bb) {
        #pragma unroll
        for (int ks = 0; ks < 2; ++ks) {
            const int ph0 = ks * 2 + (l >> 5);
            s8v ahf[2], alf[2], bhf[2], blf[2];
            #pragma unroll
            for (int m = 0; m < 2; ++m) {
                const int row = wr * 64 + m * 32 + (l & 31);
                const int ph = ph0 ^ (row & 7);
                ahf[m] = *(const s8v*)&Ab[row * 64 + ph * 8];
                alf[m] = *(const s8v*)&Ab[row * 64 + (ph ^ 4) * 8];
            }
            #pragma unroll
            for (int n = 0; n < 2; ++n) {
                const int col = wc * 64 + n * 32 + (l & 31);
                const int ph = ph0 ^ (col & 7);
                bhf[n] = *(const s8v*)&Bb[col * 64 + ph * 8];
                blf[n] = *(const s8v*)&Bb[col * 64 + (ph ^ 4) * 8];
            }
            __builtin_amdgcn_s_setprio(1);
            #pragma unroll
            for (int m = 0; m < 2; ++m)
                #pragma unroll
                for (int n = 0; n < 2; ++n) {
                    acc[m][n] = __builtin_amdgcn_mfma_f32_32x32x16_bf16(ahf[m], bhf[n], acc[m][n], 0, 0, 0);
                    acc[m][n] = __builtin_amdgcn_mfma_f32_32x32x16_bf16(ahf[m], blf[n], acc[m][n], 0, 0, 0);
                    acc[m][n] = __builtin_amdgcn_mfma_f32_32x32x16_bf16(alf[m], bhf[n], acc[m][n], 0, 0, 0);
                }
            __builtin_amdgcn_s_setprio(0);
        }
    };
    // one K-step: cvt(A regs, waits own vmem -> covers older B(t)); barrier;
    // ds_write A; issue B(t+1) then A(t+1); lgkmcnt(0); barrier; compute.
    auto step = [&](int t, short* bcur, short* bnext) {
        s8v hi0, hi1, lo0, lo1;
        #pragma unroll
        for (int e = 0; e < 4; ++e) {
            float v; short h;
            v = cur0[e]; h = f2bf(v); hi0[e]     = h; lo0[e]     = f2bf(v - bf2f(h));
            v = cur1[e]; h = f2bf(v); hi0[e + 4] = h; lo0[e + 4] = f2bf(v - bf2f(h));
            v = cur2[e]; h = f2bf(v); hi1[e]     = h; lo1[e]     = f2bf(v - bf2f(h));
            v = cur3[e]; h = f2bf(v); hi1[e + 4] = h; lo1[e + 4] = f2bf(v - bf2f(h));
        }
        __builtin_amdgcn_s_barrier();              // compute(t-1) done everywhere
        __builtin_amdgcn_sched_barrier(0);
        *(s8v*)&awr[pw0] = hi0;
        *(s8v*)&awr[pw1] = hi1;
        *(s8v*)&awr[pw2] = lo0;
        *(s8v*)&awr[pw3] = lo1;
        if (t < 63) {
            stageB(t + 1, bnext);                  // older vmem
            __builtin_amdgcn_sched_barrier(0);     // keep A-loads after B-DMA
            loadA(t + 1);                          // newer vmem
        }
        asm volatile("s_waitcnt lgkmcnt(0)" ::: "memory");
        __builtin_amdgcn_s_barrier();              // staging visible; B(t+1)/A(t+1) in flight
        __builtin_amdgcn_sched_barrier(0);
        compute(bcur);
    };

    // prologue: B(0) first (older), then A(0)
    stageB(0, Bb0);
    __builtin_amdgcn_sched_barrier(0);
    loadA(0);
    for (int t = 0; t < 64; t += 2) {
        step(t,     Bb0, Bb1);
        step(t + 1, Bb1, Bb0);
    }

    #pragma unroll
    for (int m = 0; m < 2; ++m) {
        #pragma unroll
        for (int n = 0; n < 2; ++n) {
            const int gcol = n0 + wc * 64 + n * 32 + (l & 31);
            const float bv = bias[gcol];
            #pragma unroll
            for (int r = 0; r < 16; ++r) {
                const int grow = m0 + wr * 64 + m * 32
                               + (r & 3) + 8 * (r >> 2) + 4 * (l >> 5);
                out[(size_t)grow * 512 + gcol] = gelu_f(acc[m][n][r] + bv);
            }
        }
    }
}

// ---------------------------------------------------------------------------
// Weight split: W (K x N f32) -> [2][N][Kpad] bf16 planes.
// ---------------------------------------------------------------------------
struct SplitDesc { const float* W; short* dst; int K, N, Kpad, blk0; };
struct SplitPack { SplitDesc d[9]; };

__global__ void split_all(SplitPack p) {
    const int bid = blockIdx.x;
    int i = 0;
    #pragma unroll
    for (int j = 1; j < 9; ++j) if (bid >= p.d[j].blk0) i = j;
    const SplitDesc& D = p.d[i];
    const int idx = (bid - D.blk0) * 256 + threadIdx.x;
    const int total = D.N * D.Kpad;
    if (idx >= total) return;
    const int n = idx / D.Kpad, k = idx - n * D.Kpad;
    const float v = (k < D.K) ? D.W[(size_t)k * D.N + n] : 0.0f;
    const short hs = f2bf(v);
    D.dst[idx] = hs;
    D.dst[total + idx] = f2bf(v - bf2f(hs));
}

// ---------------------------------------------------------------------------
// gemm32 (round-7): bf16x3, dbuf LDS, 2-phase prefetch, output stride.
// EPI: 0 = +bias,gelu ; 1 = +bias ; 2 = softmax64+argmax (ostr unused).
// ---------------------------------------------------------------------------
template<int BM, int BN, int EPI>
__launch_bounds__(256, 2)
__global__ void gemm32(const float* __restrict__ A, int lda,
                       const short* __restrict__ Bsp, int ldb, int NK,
                       const float* __restrict__ bias, int K, int N, int ntiles,
                       int ostr, float* __restrict__ out, float* __restrict__ out2)
{
    constexpr int MF  = BM / 64;
    constexpr int NFw = BN / 64;
    constexpr int BUF = (BM + BN) * 64;
    constexpr int FPT = BM / 8;
    constexpr int TPR = 32 / FPT;
    constexpr int nBI = BN / 32;
    __shared__ short smem[2 * BUF];

    const int tid = threadIdx.x;
    const int l   = tid & 63, wid = tid >> 6;
    const int wr  = wid >> 1, wc = wid & 1;
    const int bid = blockIdx.x;
    const int ntb = bid % ntiles, mtb = bid / ntiles;
    const int m0  = mtb * BM, n0 = ntb * BN;

    const int ar = tid / TPR, aseg = tid % TPR;
    const float* aP = A + (size_t)(m0 + ar) * lda + aseg * FPT;

    const short* bg[nBI];
    {
        const int cs = (l & 7) ^ (l >> 3);
        const int plane = cs >> 2, kslot = cs & 3;
        #pragma unroll
        for (int j = 0; j < nBI; ++j) {
            const int col = (wid * nBI + j) * 8 + (l >> 3);
            bg[j] = Bsp + (size_t)plane * NK + (size_t)(n0 + col) * ldb + kslot * 8;
        }
    }

    f16v acc[MF][NFw];
    #pragma unroll
    for (int m = 0; m < MF; ++m)
        #pragma unroll
        for (int n = 0; n < NFw; ++n) acc[m][n] = (f16v)0.0f;

    f4v areg[FPT / 4];

    auto loadA = [&](int t) {
        const float* p = aP + t * 32;
        #pragma unroll
        for (int i = 0; i < FPT / 4; ++i) areg[i] = *(const f4v*)(p + i * 4);
    };
    auto stageB = [&](int t, short* buf) {
        short* Bb = buf + BM * 64;
        #pragma unroll
        for (int j = 0; j < nBI; ++j)
            gload_lds16(bg[j] + t * 32, Bb + (wid * nBI + j) * 512);
    };
    auto writeA = [&](short* buf) {
        #pragma unroll
        for (int c = 0; c < FPT / 8; ++c) {
            s8v hi, lo;
            #pragma unroll
            for (int e = 0; e < 8; ++e) {
                const float v = areg[c * 2 + (e >> 2)][e & 3];
                const short hs = f2bf(v);
                hi[e] = hs; lo[e] = f2bf(v - bf2f(hs));
            }
            const int csh = aseg * (FPT / 8) + c;
            *(s8v*)&buf[ar * 64 + ((csh    ) ^ (ar & 7)) * 8] = hi;
            *(s8v*)&buf[ar * 64 + ((csh + 4) ^ (ar & 7)) * 8] = lo;
        }
    };
    auto compute = [&](const short* buf) {
        const short* Ab = buf;
        const short* Bb = buf + BM * 64;
        #pragma unroll
        for (int ks = 0; ks < 2; ++ks) {
            const int csb = ks * 2 + (l >> 5);
            s8v ah[MF], al[MF], bh[NFw], bl[NFw];
            #pragma unroll
            for (int m = 0; m < MF; ++m) {
                const int row = wr * (BM / 2) + m * 32 + (l & 31);
                ah[m] = *(const s8v*)&Ab[row * 64 + ((csb    ) ^ (row & 7)) * 8];
                al[m] = *(const s8v*)&Ab[row * 64 + ((csb + 4) ^ (row & 7)) * 8];
            }
            #pragma unroll
            for (int n = 0; n < NFw; ++n) {
                const int col = wc * (BN / 2) + n * 32 + (l & 31);
                bh[n] = *(const s8v*)&Bb[col * 64 + ((csb    ) ^ (col & 7)) * 8];
                bl[n] = *(const s8v*)&Bb[col * 64 + ((csb + 4) ^ (col & 7)) * 8];
            }
            __builtin_amdgcn_s_setprio(1);
            #pragma unroll
            for (int m = 0; m < MF; ++m)
                #pragma unroll
                for (int n = 0; n < NFw; ++n) {
                    acc[m][n] = __builtin_amdgcn_mfma_f32_32x32x16_bf16(ah[m], bh[n], acc[m][n], 0, 0, 0);
                    acc[m][n] = __builtin_amdgcn_mfma_f32_32x32x16_bf16(ah[m], bl[n], acc[m][n], 0, 0, 0);
                    acc[m][n] = __builtin_amdgcn_mfma_f32_32x32x16_bf16(al[m], bh[n], acc[m][n], 0, 0, 0);
                }
            __builtin_amdgcn_s_setprio(0);
        }
    };

    const int NT = K / 32;
    loadA(0);
    stageB(0, smem);
    writeA(smem);
    __syncthreads();
    for (int t = 0; t < NT; ++t) {
        short* curb = smem + (t & 1) * BUF;
        short* nxtb = smem + ((t & 1) ^ 1) * BUF;
        const bool pf = (t + 1 < NT);
        if (pf) { loadA(t + 1); stageB(t + 1, nxtb); }
        compute(curb);
        if (pf) writeA(nxtb);
        __syncthreads();
    }

    if constexpr (EPI <= 1) {
        #pragma unroll
        for (int m = 0; m < MF; ++m) {
            #pragma unroll
            for (int n = 0; n < NFw; ++n) {
                const int gcol = n0 + wc * (BN / 2) + n * 32 + (l & 31);
                const float bv = bias[gcol];
                #pragma unroll
                for (int r = 0; r < 16; ++r) {
                    const int grow = m0 + wr * (BM / 2) + m * 32
                                   + (r & 3) + 8 * (r >> 2) + 4 * (l >> 5);
                    float xv = acc[m][n][r] + bv;
                    if constexpr (EPI == 0) xv = gelu_f(xv);
                    out[(size_t)grow * ostr + gcol] = xv;
                }
            }
        }
    } else {
        float* LT = reinterpret_cast<float*>(smem);   // [64][64]
        const int gcolL = wc * 32 + (l & 31);
        const float bv = bias[gcolL];
        #pragma unroll
        for (int r = 0; r < 16; ++r) {
            const int row = wr * 32 + (r & 3) + 8 * (r >> 2) + 4 * (l >> 5);
            LT[row * 64 + gcolL] = acc[0][0][r] + bv;
        }
        __syncthreads();
        const int r = tid >> 2, q = tid & 3;
        const float* Lr = LT + r * 64 + q * 16;
        float mx = Lr[0];
        #pragma unroll
        for (int c = 1; c < 16; ++c) mx = fmaxf(mx, Lr[c]);
        mx = fmaxf(mx, __shfl_xor(mx, 1));
        mx = fmaxf(mx, __shfl_xor(mx, 2));
        float ev[16]; float s = 0.0f;
        #pragma unroll
        for (int c = 0; c < 16; ++c) { ev[c] = expf(Lr[c] - mx); s += ev[c]; }
        s += __shfl_xor(s, 1);
        s += __shfl_xor(s, 2);
        float pmax = -1.0f; int arg = 0;
        #pragma unroll
        for (int c = 0; c < 16; ++c) {
            const float pv = ev[c] / s;
            out[(size_t)(m0 + r) * 64 + q * 16 + c] = pv;
            if (pv > pmax) { pmax = pv; arg = q * 16 + c; }
        }
        #pragma unroll
        for (int off = 1; off <= 2; off <<= 1) {
            const float po = __shfl_xor(pmax, off);
            const int   ao = __shfl_xor(arg, off);
            if (po > pmax || (po == pmax && ao < arg)) { pmax = po; arg = ao; }
        }
        if (q == 0) out2[m0 + r] = (float)arg;
    }
}

// ---------------------------------------------------------------------------
// LayerNorm(256) in place (round-3).
// ---------------------------------------------------------------------------
__global__ __launch_bounds__(256) void ln_kernel(float* __restrict__ H,
                                                 const float* __restrict__ G,
                                                 const float* __restrict__ Bv)
{
    const int row = blockIdx.x * 4 + (threadIdx.x >> 6);
    const int l   = threadIdx.x & 63;
    float* hr = H + (size_t)row * 256;
    f4v v = *reinterpret_cast<const f4v*>(&hr[l * 4]);
    float s = v[0] + v[1] + v[2] + v[3];
    #pragma unroll
    for (int o = 32; o; o >>= 1) s += __shfl_xor(s, o);
    const float mu = s * 0.00390625f;
    f4v d = v - mu;
    float q = d[0]*d[0] + d[1]*d[1] + d[2]*d[2] + d[3]*d[3];
    #pragma unroll
    for (int o = 32; o; o >>= 1) q += __shfl_xor(q, o);
    const float var = q * 0.00390625f;
    const float sc  = 1.0f / sqrtf(var + 1e-5f);
    f4v gg = *reinterpret_cast<const f4v*>(&G[l * 4]);
    f4v bb = *reinterpret_cast<const f4v*>(&Bv[l * 4]);
    f4v o4 = d * sc * gg + bb;
    *reinterpret_cast<f4v*>(&hr[l * 4]) = o4;
}

// ---------------------------------------------------------------------------
// Level head (round-3 math) as device fn; p_all runs all 3 per wave.
// ---------------------------------------------------------------------------
__device__ void p_head(int row, int l,
                       const float* __restrict__ X, int din,
                       const float* __restrict__ F, int fstr,
                       const float* __restrict__ W3d, const float* __restrict__ b3d,
                       const float* __restrict__ cc,
                       const float* __restrict__ rW, const float* __restrict__ rb,
                       float* __restrict__ dst)
{
    float px0 = 0.f, px1 = 0.f, px2 = 0.f;
    const int per = din >> 6;
    const float* xr = X + (size_t)row * din;
    for (int i = 0; i < per; ++i) {
        const int k = l + (i << 6);
        const float xv = xr[k];
        px0 += xv * W3d[k*3 + 0];
        px1 += xv * W3d[k*3 + 1];
        px2 += xv * W3d[k*3 + 2];
    }
    float g0 = 0.f, g1 = 0.f, g2 = 0.f, g3 = 0.f;
    const float* fr = F + (size_t)row * fstr;
    #pragma unroll
    for (int i = 0; i < 2; ++i) {
        const int k = l + (i << 6);
        const float fv = fr[k];
        g0 += fv * rW[k*4 + 0]; g1 += fv * rW[k*4 + 1];
        g2 += fv * rW[k*4 + 2]; g3 += fv * rW[k*4 + 3];
    }
    #pragma unroll
    for (int o = 32; o; o >>= 1) {
        px0 += __shfl_xor(px0, o); px1 += __shfl_xor(px1, o); px2 += __shfl_xor(px2, o);
        g0  += __shfl_xor(g0, o);  g1  += __shfl_xor(g1, o);
        g2  += __shfl_xor(g2, o);  g3  += __shfl_xor(g3, o);
    }
    if (l == 0) {
        const float pos0 = px0 + b3d[0], pos1 = px1 + b3d[1], pos2 = px2 + b3d[2];
        float lg[4];
        float mx = -1e30f;
        float gg[4] = {g0, g1, g2, g3};
        #pragma unroll
        for (int c = 0; c < 4; ++c) {
            float a = gg[c] + rb[c]
                    + pos0 * rW[512 + c] + pos1 * rW[516 + c] + pos2 * rW[520 + c];
            const float d0 = pos0 - cc[c*3 + 0];
            const float d1 = pos1 - cc[c*3 + 1];
            const float d2 = pos2 - cc[c*3 + 2];
            a += 0.5f * (-(d0*d0 + d1*d1 + d2*d2) / 2.00000001f);
            lg[c] = a;
            mx = fmaxf(mx, a);
        }
        const float e0 = expf(lg[0]-mx), e1 = expf(lg[1]-mx),
                    e2 = expf(lg[2]-mx), e3 = expf(lg[3]-mx);
        const float s = e0 + e1 + e2 + e3;
        dst[0] = e0/s; dst[1] = e1/s; dst[2] = e2/s; dst[3] = e3/s;
    }
}

struct PAllArgs {
    const float* h2; const float* f1; const float* f2; float* comb;
    const float* W3d[3]; const float* b3d[3]; const float* cc[3];
    const float* rW[3];  const float* rb[3];
};

__global__ __launch_bounds__(256) void p_all(PAllArgs A)
{
    const int row = blockIdx.x * 4 + (threadIdx.x >> 6);
    const int l   = threadIdx.x & 63;
    float* cr = A.comb + (size_t)row * 160;
    p_head(row, l, A.h2, 256, A.f1,  128, A.W3d[0], A.b3d[0], A.cc[0], A.rW[0], A.rb[0], cr + 128);
    p_head(row, l, A.f1, 128, A.f2,  128, A.W3d[1], A.b3d[1], A.cc[1], A.rW[1], A.rb[1], cr + 132);
    p_head(row, l, A.f2, 128, A.comb, 160, A.W3d[2], A.b3d[2], A.cc[2], A.rW[2], A.rb[2], cr + 136);
}

// ---------------------------------------------------------------------------
extern "C" void kernel_launch(void* const* d_in, const int* in_sizes, int n_in,
                              void* d_out, int out_size, void* d_ws, size_t ws_size,
                              hipStream_t stream)
{
    (void)in_sizes; (void)n_in; (void)out_size; (void)ws_size;

    const float* x    = (const float*)d_in[0];
    const float* ipW1 = (const float*)d_in[1];
    const float* ipb1 = (const float*)d_in[2];
    const float* ipW2 = (const float*)d_in[3];
    const float* ipb2 = (const float*)d_in[4];
    const float* ln_g = (const float*)d_in[5];
    const float* ln_b = (const float*)d_in[6];
    const float* W3d[3] = {(const float*)d_in[7],  (const float*)d_in[17], (const float*)d_in[27]};
    const float* b3d[3] = {(const float*)d_in[8],  (const float*)d_in[18], (const float*)d_in[28]};
    const float* cc[3]  = {(const float*)d_in[9],  (const float*)d_in[19], (const float*)d_in[29]};
    const float* f1W[3] = {(const float*)d_in[11], (const float*)d_in[21], (const float*)d_in[31]};
    const float* f1b[3] = {(const float*)d_in[12], (const float*)d_in[22], (const float*)d_in[32]};
    const float* f2W[3] = {(const float*)d_in[13], (const float*)d_in[23], (const float*)d_in[33]};
    const float* f2b[3] = {(const float*)d_in[14], (const float*)d_in[24], (const float*)d_in[34]};
    const float* rW[3]  = {(const float*)d_in[15], (const float*)d_in[25], (const float*)d_in[35]};
    const float* rb[3]  = {(const float*)d_in[16], (const float*)d_in[26], (const float*)d_in[36]};
    const float* ehW1 = (const float*)d_in[37];
    const float* ehb1 = (const float*)d_in[38];
    const float* ehW2 = (const float*)d_in[39];
    const float* ehb2 = (const float*)d_in[40];

    size_t off = 0;
    auto take = [&](size_t bytes) -> void* {
        void* p = (char*)d_ws + off;
        off += (bytes + 255) & ~(size_t)255;
        return p;
    };
    auto takeW = [&](int N, int Kpad) -> short* {
        return (short*)take((size_t)2 * N * Kpad * 2);
    };
    short* W1img = (short*)take((size_t)64 * 512 * 64 * 2);   // 4 MiB
    short* W2s = takeW(256, 512);
    short* L1a = takeW(128, 256);
    short* L1b = takeW(128, 128);
    short* L2a = takeW(128, 128);
    short* L2b = takeW(128, 128);
    short* L3a = takeW(128, 128);
    short* L3b = takeW(128, 128);
    short* E1s = takeW(256, 160);
    short* E2s = takeW(64, 256);
    float* h1  = (float*)take((size_t)B_ROWS * 512 * 4);
    float* h2  = (float*)take((size_t)B_ROWS * 256 * 4);
    float* zg  = (float*)take((size_t)B_ROWS * 128 * 4);
    float* f1  = (float*)take((size_t)B_ROWS * 128 * 4);
    float* f2  = (float*)take((size_t)B_ROWS * 128 * 4);
    float* geh = (float*)take((size_t)B_ROWS * 256 * 4);
    float* comb = h1;                              // [B][160], h1 dead after gemm2

    // ---- weight pre-passes ----
    split_w1_img<<<(64 * 512 * 8) / 256, 256, 0, stream>>>(ipW1, W1img);
    SplitPack sp;
    int blk = 0;
    auto desc = [&](int i, const float* W, short* dst, int K, int N, int Kpad) {
        sp.d[i] = {W, dst, K, N, Kpad, blk};
        blk += (N * Kpad + 255) / 256;
    };
    desc(0, ipW2,   W2s,  512, 256,  512);
    desc(1, f1W[0], L1a,  256, 128,  256);
    desc(2, f2W[0], L1b,  128, 128,  128);
    desc(3, f1W[1], L2a,  128, 128,  128);
    desc(4, f2W[1], L2b,  128, 128,  128);
    desc(5, f1W[2], L3a,  128, 128,  128);
    desc(6, f2W[2], L3b,  128, 128,  128);
    desc(7, ehW1,   E1s,  140, 256,  160);
    desc(8, ehW2,   E2s,  256,  64,  256);
    split_all<<<blk, 256, 0, stream>>>(sp);

    const dim3 blkT(256);
    constexpr int MG128 = B_ROWS / 128;  // 256
    constexpr int MG64  = B_ROWS / 64;   // 512

    // input_proj
    gemm1k<<<1024, blkT, 0, stream>>>(x, W1img, ipb1, h1);
    gemm32<128,128,1><<<MG128*2, blkT, 0, stream>>>(h1, 512, W2s, 512, 256*512, ipb2,
                                                    512, 256, 2, 256, h2, nullptr);
    ln_kernel<<<B_ROWS/4, 256, 0, stream>>>(h2, ln_g, ln_b);

    // levels (gemm pairs; L3b writes f3 straight into comb at stride 160)
    gemm32<64,128,0><<<MG64, blkT, 0, stream>>>(h2, 256, L1a, 256, 128*256, f1b[0], 256, 128, 1, 128, zg, nullptr);
    gemm32<64,128,1><<<MG64, blkT, 0, stream>>>(zg, 128, L1b, 128, 128*128, f2b[0], 128, 128, 1, 128, f1, nullptr);
    gemm32<64,128,0><<<MG64, blkT, 0, stream>>>(f1, 128, L2a, 128, 128*128, f1b[1], 128, 128, 1, 128, zg, nullptr);
    gemm32<64,128,1><<<MG64, blkT, 0, stream>>>(zg, 128, L2b, 128, 128*128, f2b[1], 128, 128, 1, 128, f2, nullptr);
    gemm32<64,128,0><<<MG64, blkT, 0, stream>>>(f2, 128, L3a, 128, 128*128, f1b[2], 128, 128, 1, 128, zg, nullptr);
    gemm32<64,128,1><<<MG64, blkT, 0, stream>>>(zg, 128, L3b, 128, 128*128, f2b[2], 128, 128, 1, 160, comb, nullptr);

    // all three p-heads in one launch (inputs h2,f1,f2,comb all ready)
    PAllArgs pa;
    pa.h2 = h2; pa.f1 = f1; pa.f2 = f2; pa.comb = comb;
    for (int i = 0; i < 3; ++i) {
        pa.W3d[i] = W3d[i]; pa.b3d[i] = b3d[i]; pa.cc[i] = cc[i];
        pa.rW[i] = rW[i];   pa.rb[i] = rb[i];
    }
    p_all<<<B_ROWS/4, 256, 0, stream>>>(pa);

    // expert head (comb cols 140-159 stale but hit zero E1 pad rows)
    gemm32<64,128,0><<<MG64*2, blkT, 0, stream>>>(comb, 160, E1s, 160, 256*160, ehb1,
                                                  160, 256, 2, 256, geh, nullptr);
    gemm32<64,64,2><<<MG64, blkT, 0, stream>>>(geh, 256, E2s, 256, 64*256, ehb2,
                                               256, 64, 1, 64, (float*)d_out,
                                               (float*)d_out + (size_t)B_ROWS * 64);
}